// Round 1
// baseline (5569.310 us; speedup 1.0000x reference)
//
#include <hip/hip_runtime.h>
#include <hip/hip_bf16.h>

#define NN   100000
#define NE   50000
#define NNZP 1600000
#define DD   128

// ---------------- K1: Xp = X @ W  (W cached in LDS) ----------------
__global__ __launch_bounds__(256) void gemm_xw(const float* __restrict__ X,
                                               const float* __restrict__ W,
                                               float* __restrict__ Xp) {
    __shared__ float Wl[DD * DD];      // 64 KB
    __shared__ float Xrow[8][DD];      // 4 KB
    for (int i = threadIdx.x; i < DD * DD / 4; i += 256)
        reinterpret_cast<float4*>(Wl)[i] = reinterpret_cast<const float4*>(W)[i];

    const int lane_c = threadIdx.x & 31;   // 4-col group
    const int sub_r  = threadIdx.x >> 5;   // row within 8-row chunk

    for (int base = blockIdx.x * 8; base < NN; base += gridDim.x * 8) {
        __syncthreads();
        {   // stage 8 rows of X (1024 floats = 256 float4)
            int r = threadIdx.x >> 5, c4 = threadIdx.x & 31;
            int row = base + r;
            float4 v = make_float4(0.f, 0.f, 0.f, 0.f);
            if (row < NN) v = reinterpret_cast<const float4*>(X + (size_t)row * DD)[c4];
            reinterpret_cast<float4*>(&Xrow[r][0])[c4] = v;
        }
        __syncthreads();
        int row = base + sub_r;
        if (row >= NN) continue;
        float4 acc = make_float4(0.f, 0.f, 0.f, 0.f);
        const float* xr = &Xrow[sub_r][0];
        #pragma unroll 8
        for (int k = 0; k < DD; ++k) {
            float  xk = xr[k];
            float4 w  = reinterpret_cast<const float4*>(&Wl[k * DD])[lane_c];
            acc.x = fmaf(xk, w.x, acc.x);
            acc.y = fmaf(xk, w.y, acc.y);
            acc.z = fmaf(xk, w.z, acc.z);
            acc.w = fmaf(xk, w.w, acc.w);
        }
        reinterpret_cast<float4*>(Xp + (size_t)row * DD)[lane_c] = acc;
    }
}

// ---------------- K2: scatter-sum Xp[vertex] -> XeSum[edges], count ----------------
__global__ __launch_bounds__(256) void scatter_edges(const float* __restrict__ Xp,
                                                     const int* __restrict__ vertex,
                                                     const int* __restrict__ edges,
                                                     float* __restrict__ XeSum,
                                                     float* __restrict__ cnt) {
    int pair = blockIdx.x * 8 + (threadIdx.x >> 5);
    if (pair >= NNZP) return;
    int lane = threadIdx.x & 31;
    int v = vertex[pair];
    int e = edges[pair];
    float4 val = reinterpret_cast<const float4*>(Xp + (size_t)v * DD)[lane];
    float* dst = XeSum + (size_t)e * DD + lane * 4;
    atomicAdd(dst + 0, val.x);
    atomicAdd(dst + 1, val.y);
    atomicAdd(dst + 2, val.z);
    atomicAdd(dst + 3, val.w);
    if (lane == 0) atomicAdd(cnt + e, 1.0f);
}

// ---------------- K3: Xe = XeSum / max(cnt,1)  (in place, in d_out) ----------------
__global__ __launch_bounds__(256) void finalize_xe(float* __restrict__ Xe,
                                                   const float* __restrict__ cnt) {
    int i = blockIdx.x * 256 + threadIdx.x;   // over E*D/4 float4s
    if (i >= NE * DD / 4) return;
    int e = i >> 5;                            // D/4 == 32
    float inv = 1.0f / fmaxf(cnt[e], 1.0f);
    float4 v = reinterpret_cast<float4*>(Xe)[i];
    v.x *= inv; v.y *= inv; v.z *= inv; v.w *= inv;
    reinterpret_cast<float4*>(Xe)[i] = v;
}

// ---------------- K4: scatter-sum Xe[edges] -> Xv[vertex] (accum in d_out) --------
__global__ __launch_bounds__(256) void scatter_vertices(const float* __restrict__ Xe,
                                                        const int* __restrict__ vertex,
                                                        const int* __restrict__ edges,
                                                        float* __restrict__ Xv) {
    int pair = blockIdx.x * 8 + (threadIdx.x >> 5);
    if (pair >= NNZP) return;
    int lane = threadIdx.x & 31;
    int v = vertex[pair];
    int e = edges[pair];
    float4 val = reinterpret_cast<const float4*>(Xe + (size_t)e * DD)[lane];
    float* dst = Xv + (size_t)v * DD + lane * 4;
    atomicAdd(dst + 0, val.x);
    atomicAdd(dst + 1, val.y);
    atomicAdd(dst + 2, val.z);
    atomicAdd(dst + 3, val.w);
}

// ---------------- K5: out = normalize((1+eps)*Xp + Xv) ----------------
__global__ __launch_bounds__(256) void finalize_out(const float* __restrict__ Xp,
                                                    float* __restrict__ Out,
                                                    const float* __restrict__ eps) {
    int row = blockIdx.x * 8 + (threadIdx.x >> 5);
    if (row >= NN) return;
    int lane = threadIdx.x & 31;
    float g = 1.0f + eps[0];
    float4 xp = reinterpret_cast<const float4*>(Xp + (size_t)row * DD)[lane];
    float4 xv = reinterpret_cast<const float4*>(Out + (size_t)row * DD)[lane];
    float4 o;
    o.x = fmaf(g, xp.x, xv.x);
    o.y = fmaf(g, xp.y, xv.y);
    o.z = fmaf(g, xp.z, xv.z);
    o.w = fmaf(g, xp.w, xv.w);
    float ss = o.x * o.x + o.y * o.y + o.z * o.z + o.w * o.w;
    #pragma unroll
    for (int off = 1; off < 32; off <<= 1) ss += __shfl_xor(ss, off, 64);
    float inv = 1.0f / fmaxf(sqrtf(ss), 1e-12f);
    o.x *= inv; o.y *= inv; o.z *= inv; o.w *= inv;
    reinterpret_cast<float4*>(Out + (size_t)row * DD)[lane] = o;
}

extern "C" void kernel_launch(void* const* d_in, const int* in_sizes, int n_in,
                              void* d_out, int out_size, void* d_ws, size_t ws_size,
                              hipStream_t stream) {
    const float* X      = (const float*)d_in[0];
    const float* W      = (const float*)d_in[1];
    const float* eps    = (const float*)d_in[2];
    const int*   vertex = (const int*)d_in[3];
    const int*   edges  = (const int*)d_in[4];

    float* out = (float*)d_out;                 // [N,D] then [E,D]
    float* Xe  = out + (size_t)NN * DD;         // Xe output region doubles as XeSum accumulator
    float* Xp  = (float*)d_ws;                  // N*D floats (51.2 MB)
    float* cnt = Xp + (size_t)NN * DD;          // E floats

    // zero accumulators (d_out is poisoned, not re-poisoned between replays)
    hipMemsetAsync(d_out, 0, (size_t)out_size * sizeof(float), stream);
    hipMemsetAsync(cnt, 0, NE * sizeof(float), stream);

    gemm_xw<<<1280, 256, 0, stream>>>(X, W, Xp);
    scatter_edges<<<NNZP / 8, 256, 0, stream>>>(Xp, vertex, edges, Xe, cnt);
    finalize_xe<<<NE * DD / 4 / 256, 256, 0, stream>>>(Xe, cnt);
    scatter_vertices<<<NNZP / 8, 256, 0, stream>>>(Xe, vertex, edges, out);
    finalize_out<<<NN / 8, 256, 0, stream>>>(Xp, out, eps);
}

// Round 2
// 1075.865 us; speedup vs baseline: 5.1766x; 5.1766x over previous
//
#include <hip/hip_runtime.h>
#include <hip/hip_bf16.h>

#define NN   100000
#define NE   50000
#define NNZP 1600000
#define DD   128

// ---------------- K1: Xp = X @ W  (W cached in LDS) ----------------
__global__ __launch_bounds__(256) void gemm_xw(const float* __restrict__ X,
                                               const float* __restrict__ W,
                                               float* __restrict__ Xp) {
    __shared__ float Wl[DD * DD];      // 64 KB
    __shared__ float Xrow[8][DD];      // 4 KB
    for (int i = threadIdx.x; i < DD * DD / 4; i += 256)
        reinterpret_cast<float4*>(Wl)[i] = reinterpret_cast<const float4*>(W)[i];

    const int lane_c = threadIdx.x & 31;
    const int sub_r  = threadIdx.x >> 5;

    for (int base = blockIdx.x * 8; base < NN; base += gridDim.x * 8) {
        __syncthreads();
        {
            int r = threadIdx.x >> 5, c4 = threadIdx.x & 31;
            int row = base + r;
            float4 v = make_float4(0.f, 0.f, 0.f, 0.f);
            if (row < NN) v = reinterpret_cast<const float4*>(X + (size_t)row * DD)[c4];
            reinterpret_cast<float4*>(&Xrow[r][0])[c4] = v;
        }
        __syncthreads();
        int row = base + sub_r;
        if (row >= NN) continue;
        float4 acc = make_float4(0.f, 0.f, 0.f, 0.f);
        const float* xr = &Xrow[sub_r][0];
        #pragma unroll 8
        for (int k = 0; k < DD; ++k) {
            float  xk = xr[k];
            float4 w  = reinterpret_cast<const float4*>(&Wl[k * DD])[lane_c];
            acc.x = fmaf(xk, w.x, acc.x);
            acc.y = fmaf(xk, w.y, acc.y);
            acc.z = fmaf(xk, w.z, acc.z);
            acc.w = fmaf(xk, w.w, acc.w);
        }
        reinterpret_cast<float4*>(Xp + (size_t)row * DD)[lane_c] = acc;
    }
}

// ---------------- K2: histogram of edge and vertex degrees ----------------
__global__ __launch_bounds__(256) void hist(const int* __restrict__ vertex,
                                            const int* __restrict__ edges,
                                            int* __restrict__ ecnt,
                                            int* __restrict__ vcnt) {
    int i = blockIdx.x * 256 + threadIdx.x;
    if (i >= NNZP) return;
    atomicAdd(&ecnt[edges[i]], 1);
    atomicAdd(&vcnt[vertex[i]], 1);
}

// ---------------- K3: single-block exclusive scan; cnt becomes cursor -------
template <int NSEG>
__global__ __launch_bounds__(1024) void scan_excl(int* __restrict__ cnt,
                                                  int* __restrict__ off) {
    __shared__ int part[1024];
    const int t  = threadIdx.x;
    const int CH = (NSEG + 1023) / 1024;
    const int lo = t * CH;
    const int hi = (lo + CH < NSEG) ? lo + CH : NSEG;
    int s = 0;
    for (int i = lo; i < hi; ++i) s += cnt[i];
    part[t] = s;
    __syncthreads();
    #pragma unroll
    for (int d = 1; d < 1024; d <<= 1) {
        int v = (t >= d) ? part[t - d] : 0;
        __syncthreads();
        part[t] += v;
        __syncthreads();
    }
    int running = (t == 0) ? 0 : part[t - 1];
    for (int i = lo; i < hi; ++i) {
        int c = cnt[i];
        off[i] = running;
        cnt[i] = running;   // cursor for placement pass
        running += c;
    }
    if (t == 1023) off[NSEG] = part[1023];
}

// ---------------- K4: placement — build both CSR adjacency lists ----------
__global__ __launch_bounds__(256) void place(const int* __restrict__ vertex,
                                             const int* __restrict__ edges,
                                             int* __restrict__ ecur,
                                             int* __restrict__ vcur,
                                             int* __restrict__ vlist,
                                             int* __restrict__ elist) {
    int i = blockIdx.x * 256 + threadIdx.x;
    if (i >= NNZP) return;
    int v = vertex[i];
    int e = edges[i];
    int pe = atomicAdd(&ecur[e], 1);
    vlist[pe] = v;
    int pv = atomicAdd(&vcur[v], 1);
    elist[pv] = e;
}

// ---------------- K5: Xe[e] = mean over CSR of Xp rows ----------------
__global__ __launch_bounds__(256) void edge_gather(const float* __restrict__ Xp,
                                                   const int* __restrict__ eoff,
                                                   const int* __restrict__ vlist,
                                                   float* __restrict__ Xe) {
    int e = blockIdx.x * 8 + (threadIdx.x >> 5);
    if (e >= NE) return;
    int lane = threadIdx.x & 31;
    int start = eoff[e], end = eoff[e + 1];
    float4 a0 = make_float4(0.f, 0.f, 0.f, 0.f);
    float4 a1 = make_float4(0.f, 0.f, 0.f, 0.f);
    int j = start;
    for (; j + 1 < end; j += 2) {
        int v0 = vlist[j], v1 = vlist[j + 1];
        float4 x0 = reinterpret_cast<const float4*>(Xp + (size_t)v0 * DD)[lane];
        float4 x1 = reinterpret_cast<const float4*>(Xp + (size_t)v1 * DD)[lane];
        a0.x += x0.x; a0.y += x0.y; a0.z += x0.z; a0.w += x0.w;
        a1.x += x1.x; a1.y += x1.y; a1.z += x1.z; a1.w += x1.w;
    }
    if (j < end) {
        int v0 = vlist[j];
        float4 x0 = reinterpret_cast<const float4*>(Xp + (size_t)v0 * DD)[lane];
        a0.x += x0.x; a0.y += x0.y; a0.z += x0.z; a0.w += x0.w;
    }
    float inv = 1.0f / fmaxf((float)(end - start), 1.0f);
    float4 o;
    o.x = (a0.x + a1.x) * inv;
    o.y = (a0.y + a1.y) * inv;
    o.z = (a0.z + a1.z) * inv;
    o.w = (a0.w + a1.w) * inv;
    reinterpret_cast<float4*>(Xe + (size_t)e * DD)[lane] = o;
}

// -------- K6: Xv[v] = sum Xe rows; out = normalize((1+eps)*Xp + Xv) --------
__global__ __launch_bounds__(256) void vertex_gather_out(const float* __restrict__ Xp,
                                                         const float* __restrict__ Xe,
                                                         const int* __restrict__ voff,
                                                         const int* __restrict__ elist,
                                                         const float* __restrict__ eps,
                                                         float* __restrict__ Out) {
    int v = blockIdx.x * 8 + (threadIdx.x >> 5);
    if (v >= NN) return;
    int lane = threadIdx.x & 31;
    int start = voff[v], end = voff[v + 1];
    float4 a0 = make_float4(0.f, 0.f, 0.f, 0.f);
    float4 a1 = make_float4(0.f, 0.f, 0.f, 0.f);
    int j = start;
    for (; j + 1 < end; j += 2) {
        int e0 = elist[j], e1 = elist[j + 1];
        float4 x0 = reinterpret_cast<const float4*>(Xe + (size_t)e0 * DD)[lane];
        float4 x1 = reinterpret_cast<const float4*>(Xe + (size_t)e1 * DD)[lane];
        a0.x += x0.x; a0.y += x0.y; a0.z += x0.z; a0.w += x0.w;
        a1.x += x1.x; a1.y += x1.y; a1.z += x1.z; a1.w += x1.w;
    }
    if (j < end) {
        int e0 = elist[j];
        float4 x0 = reinterpret_cast<const float4*>(Xe + (size_t)e0 * DD)[lane];
        a0.x += x0.x; a0.y += x0.y; a0.z += x0.z; a0.w += x0.w;
    }
    float g = 1.0f + eps[0];
    float4 xp = reinterpret_cast<const float4*>(Xp + (size_t)v * DD)[lane];
    float4 o;
    o.x = fmaf(g, xp.x, a0.x + a1.x);
    o.y = fmaf(g, xp.y, a0.y + a1.y);
    o.z = fmaf(g, xp.z, a0.z + a1.z);
    o.w = fmaf(g, xp.w, a0.w + a1.w);
    float ss = o.x * o.x + o.y * o.y + o.z * o.z + o.w * o.w;
    #pragma unroll
    for (int off = 1; off < 32; off <<= 1) ss += __shfl_xor(ss, off, 64);
    float inv = 1.0f / fmaxf(sqrtf(ss), 1e-12f);
    o.x *= inv; o.y *= inv; o.z *= inv; o.w *= inv;
    reinterpret_cast<float4*>(Out + (size_t)v * DD)[lane] = o;
}

extern "C" void kernel_launch(void* const* d_in, const int* in_sizes, int n_in,
                              void* d_out, int out_size, void* d_ws, size_t ws_size,
                              hipStream_t stream) {
    const float* X      = (const float*)d_in[0];
    const float* W      = (const float*)d_in[1];
    const float* eps    = (const float*)d_in[2];
    const int*   vertex = (const int*)d_in[3];
    const int*   edges  = (const int*)d_in[4];

    float* out = (float*)d_out;                 // [N,D]
    float* Xe  = out + (size_t)NN * DD;         // [E,D] (second output region)

    // workspace layout
    float* Xp    = (float*)d_ws;                         // N*D floats
    int*   ecnt  = (int*)(Xp + (size_t)NN * DD);         // E   (becomes cursor)
    int*   vcnt  = ecnt + NE;                            // N   (becomes cursor)
    int*   eoff  = vcnt + NN;                            // E+1
    int*   voff  = eoff + NE + 1;                        // N+1
    int*   vlist = voff + NN + 1;                        // NNZ
    int*   elist = vlist + NNZP;                         // NNZ

    // zero the degree counters (ecnt and vcnt are contiguous)
    hipMemsetAsync(ecnt, 0, (size_t)(NE + NN) * sizeof(int), stream);

    gemm_xw<<<1280, 256, 0, stream>>>(X, W, Xp);
    hist<<<NNZP / 256, 256, 0, stream>>>(vertex, edges, ecnt, vcnt);
    scan_excl<NE><<<1, 1024, 0, stream>>>(ecnt, eoff);
    scan_excl<NN><<<1, 1024, 0, stream>>>(vcnt, voff);
    place<<<NNZP / 256, 256, 0, stream>>>(vertex, edges, ecnt, vcnt, vlist, elist);
    edge_gather<<<NE / 8, 256, 0, stream>>>(Xp, eoff, vlist, Xe);
    vertex_gather_out<<<NN / 8, 256, 0, stream>>>(Xp, Xe, voff, elist, eps, out);
}

// Round 4
// 632.767 us; speedup vs baseline: 8.8015x; 1.7003x over previous
//
#include <hip/hip_runtime.h>
#include <hip/hip_bf16.h>

#define NN   100000
#define NE   50000
#define NNZP 1600000
#define DD   128
#define NXCD 8
#define EBIN (NE / NXCD)     // 6250
#define VBIN (NN / NXCD)     // 12500

typedef __attribute__((ext_vector_type(8))) short bf16x8;
typedef __attribute__((ext_vector_type(4))) float f32x4;

__device__ __forceinline__ ushort f2bf(float f) {
    __hip_bfloat16 h = __float2bfloat16(f);
    return *reinterpret_cast<ushort*>(&h);
}
__device__ __forceinline__ float bf2f(ushort u) {
    union { unsigned int i; float f; } x; x.i = ((unsigned int)u) << 16; return x.f;
}

// ---------------- K0: Wt16[n][k] = bf16(W[k][n]) ----------------
__global__ __launch_bounds__(256) void convertWt(const float* __restrict__ W,
                                                 ushort* __restrict__ Wt) {
    int i = blockIdx.x * 256 + threadIdx.x;   // 16384 elems, k-major
    if (i >= DD * DD) return;
    int k = i >> 7, n = i & 127;
    Wt[n * DD + k] = f2bf(W[i]);
}

// ---------------- K1: Xp16 = bf16( X @ W ) via MFMA ----------------
__global__ __launch_bounds__(256) void gemm_mfma(const float* __restrict__ X,
                                                 const ushort* __restrict__ Wt,
                                                 ushort* __restrict__ Xp16) {
    __shared__ char WtL[DD * DD * 2];   // 32 KB, XOR-swizzled 16B chunks
    // 2048 16B chunks; each 256B row of Wt = 16 chunks.  (bugfix: was >>3/&7)
    for (int c = threadIdx.x; c < 2048; c += 256) {
        int n = c >> 4, kc = c & 15;
        int dst = (n * 256 + kc * 16) ^ ((n & 7) << 4);
        *reinterpret_cast<int4*>(WtL + dst) = reinterpret_cast<const int4*>(Wt)[c];
    }
    __syncthreads();
    int wave = threadIdx.x >> 6;
    int lane = threadIdx.x & 63;
    int rowTile = blockIdx.x * 4 + wave;
    if (rowTile >= NN / 16) return;
    int r = lane & 15, half = lane >> 4;
    const float* xrow = X + (size_t)(rowTile * 16 + r) * DD;
    f32x4 acc[8];
    #pragma unroll
    for (int nt = 0; nt < 8; ++nt) acc[nt] = (f32x4)(0.f);
    #pragma unroll
    for (int kk = 0; kk < DD; kk += 32) {
        int kbase = kk + half * 8;
        float4 xa = *reinterpret_cast<const float4*>(xrow + kbase);
        float4 xb = *reinterpret_cast<const float4*>(xrow + kbase + 4);
        bf16x8 a;
        a[0] = (short)f2bf(xa.x); a[1] = (short)f2bf(xa.y);
        a[2] = (short)f2bf(xa.z); a[3] = (short)f2bf(xa.w);
        a[4] = (short)f2bf(xb.x); a[5] = (short)f2bf(xb.y);
        a[6] = (short)f2bf(xb.z); a[7] = (short)f2bf(xb.w);
        #pragma unroll
        for (int nt = 0; nt < 8; ++nt) {
            int n = nt * 16 + r;
            int off = (n * 256 + kbase * 2) ^ ((n & 7) << 4);
            bf16x8 b = *reinterpret_cast<const bf16x8*>(WtL + off);
            acc[nt] = __builtin_amdgcn_mfma_f32_16x16x32_bf16(a, b, acc[nt], 0, 0, 0);
        }
    }
    int row0 = rowTile * 16 + half * 4;   // C/D: col=lane&15, row=(lane>>4)*4+q
    #pragma unroll
    for (int nt = 0; nt < 8; ++nt)
        #pragma unroll
        for (int q = 0; q < 4; ++q)
            Xp16[(size_t)(row0 + q) * DD + nt * 16 + r] = f2bf(acc[nt][q]);
}

// ---------------- K2: degree histograms ----------------
__global__ __launch_bounds__(256) void hist(const int* __restrict__ vertex,
                                            const int* __restrict__ edges,
                                            int* __restrict__ ecnt,
                                            int* __restrict__ vcnt) {
    int i0 = (blockIdx.x * 256 + threadIdx.x) * 4;
    if (i0 >= NNZP) return;
    int4 e4 = *reinterpret_cast<const int4*>(edges + i0);
    int4 v4 = *reinterpret_cast<const int4*>(vertex + i0);
    atomicAdd(&ecnt[e4.x], 1); atomicAdd(&ecnt[e4.y], 1);
    atomicAdd(&ecnt[e4.z], 1); atomicAdd(&ecnt[e4.w], 1);
    atomicAdd(&vcnt[v4.x], 1); atomicAdd(&vcnt[v4.y], 1);
    atomicAdd(&vcnt[v4.z], 1); atomicAdd(&vcnt[v4.w], 1);
}

// ---------------- K3: two exclusive scans, one kernel (block 0: E, block 1: N) ----
__global__ __launch_bounds__(1024) void scan2(int* __restrict__ ecnt, int* __restrict__ eoff,
                                              int* __restrict__ vcnt, int* __restrict__ voff) {
    int* cnt; int* off; int nseg;
    if (blockIdx.x == 0) { cnt = ecnt; off = eoff; nseg = NE; }
    else                 { cnt = vcnt; off = voff; nseg = NN; }
    __shared__ int part[1024];
    const int t  = threadIdx.x;
    const int CH = (nseg + 1023) >> 10;
    const int lo = t * CH;
    const int hi = (lo + CH < nseg) ? lo + CH : nseg;
    int s = 0;
    for (int i = lo; i < hi; ++i) s += cnt[i];
    part[t] = s;
    __syncthreads();
    for (int d = 1; d < 1024; d <<= 1) {
        int v = (t >= d) ? part[t - d] : 0;
        __syncthreads();
        part[t] += v;
        __syncthreads();
    }
    int running = (t == 0) ? 0 : part[t - 1];
    for (int i = lo; i < hi; ++i) {
        int c = cnt[i];
        off[i] = running;
        cnt[i] = running;    // cursor for placement pass
        running += c;
    }
    if (t == 1023) off[nseg] = part[1023];
}

// ---------------- K4: XCD-binned placement ----------------
#define PCHUNK 4096
__global__ __launch_bounds__(256) void place_binned(const int* __restrict__ vertex,
                                                    const int* __restrict__ edges,
                                                    int* __restrict__ ecur,
                                                    int* __restrict__ vcur,
                                                    int* __restrict__ vlist,
                                                    int* __restrict__ elist) {
    int xcd   = blockIdx.x & 7;
    int chunk = blockIdx.x >> 3;
    int base  = chunk * PCHUNK;
    int end   = base + PCHUNK; if (end > NNZP) end = NNZP;
    const int elo = xcd * EBIN, ehi = elo + EBIN;
    const int vlo = xcd * VBIN, vhi = vlo + VBIN;
    for (int i = base + threadIdx.x * 4; i + 3 < end; i += 1024) {
        int4 vv = *reinterpret_cast<const int4*>(vertex + i);
        int4 ee = *reinterpret_cast<const int4*>(edges + i);
        #define PLACE1(E, V)                                              \
            if ((E) >= elo && (E) < ehi) vlist[atomicAdd(&ecur[E], 1)] = (V); \
            if ((V) >= vlo && (V) < vhi) elist[atomicAdd(&vcur[V], 1)] = (E);
        PLACE1(ee.x, vv.x) PLACE1(ee.y, vv.y) PLACE1(ee.z, vv.z) PLACE1(ee.w, vv.w)
        #undef PLACE1
    }
}

// ---------------- K5: Xe[e] = mean of Xp16 rows; also Xe16 ----------------
__global__ __launch_bounds__(256) void edge_gather(const ushort* __restrict__ Xp16,
                                                   const int* __restrict__ eoff,
                                                   const int* __restrict__ vlist,
                                                   float* __restrict__ Xe,
                                                   ushort* __restrict__ Xe16) {
    int e = blockIdx.x * 8 + (threadIdx.x >> 5);
    if (e >= NE) return;
    int lane = threadIdx.x & 31;
    int start = eoff[e], end = eoff[e + 1];
    float ax = 0.f, ay = 0.f, az = 0.f, aw = 0.f;
    int j = start;
    for (; j + 3 < end; j += 4) {
        int v0 = vlist[j], v1 = vlist[j + 1], v2 = vlist[j + 2], v3 = vlist[j + 3];
        ushort4 x0 = *reinterpret_cast<const ushort4*>(Xp16 + (size_t)v0 * DD + lane * 4);
        ushort4 x1 = *reinterpret_cast<const ushort4*>(Xp16 + (size_t)v1 * DD + lane * 4);
        ushort4 x2 = *reinterpret_cast<const ushort4*>(Xp16 + (size_t)v2 * DD + lane * 4);
        ushort4 x3 = *reinterpret_cast<const ushort4*>(Xp16 + (size_t)v3 * DD + lane * 4);
        ax += bf2f(x0.x) + bf2f(x1.x) + bf2f(x2.x) + bf2f(x3.x);
        ay += bf2f(x0.y) + bf2f(x1.y) + bf2f(x2.y) + bf2f(x3.y);
        az += bf2f(x0.z) + bf2f(x1.z) + bf2f(x2.z) + bf2f(x3.z);
        aw += bf2f(x0.w) + bf2f(x1.w) + bf2f(x2.w) + bf2f(x3.w);
    }
    for (; j < end; ++j) {
        int v0 = vlist[j];
        ushort4 x0 = *reinterpret_cast<const ushort4*>(Xp16 + (size_t)v0 * DD + lane * 4);
        ax += bf2f(x0.x); ay += bf2f(x0.y); az += bf2f(x0.z); aw += bf2f(x0.w);
    }
    float inv = 1.0f / fmaxf((float)(end - start), 1.0f);
    float4 o = make_float4(ax * inv, ay * inv, az * inv, aw * inv);
    *reinterpret_cast<float4*>(Xe + (size_t)e * DD + lane * 4) = o;
    ushort4 h;
    h.x = f2bf(o.x); h.y = f2bf(o.y); h.z = f2bf(o.z); h.w = f2bf(o.w);
    *reinterpret_cast<ushort4*>(Xe16 + (size_t)e * DD + lane * 4) = h;
}

// -------- K6: Xv = sum Xe16 rows; out = normalize((1+eps)*Xp + Xv) --------
__global__ __launch_bounds__(256) void vertex_gather_out(const ushort* __restrict__ Xp16,
                                                         const ushort* __restrict__ Xe16,
                                                         const int* __restrict__ voff,
                                                         const int* __restrict__ elist,
                                                         const float* __restrict__ eps,
                                                         float* __restrict__ Out) {
    int v = blockIdx.x * 8 + (threadIdx.x >> 5);
    if (v >= NN) return;
    int lane = threadIdx.x & 31;
    int start = voff[v], end = voff[v + 1];
    float ax = 0.f, ay = 0.f, az = 0.f, aw = 0.f;
    int j = start;
    for (; j + 3 < end; j += 4) {
        int e0 = elist[j], e1 = elist[j + 1], e2 = elist[j + 2], e3 = elist[j + 3];
        ushort4 x0 = *reinterpret_cast<const ushort4*>(Xe16 + (size_t)e0 * DD + lane * 4);
        ushort4 x1 = *reinterpret_cast<const ushort4*>(Xe16 + (size_t)e1 * DD + lane * 4);
        ushort4 x2 = *reinterpret_cast<const ushort4*>(Xe16 + (size_t)e2 * DD + lane * 4);
        ushort4 x3 = *reinterpret_cast<const ushort4*>(Xe16 + (size_t)e3 * DD + lane * 4);
        ax += bf2f(x0.x) + bf2f(x1.x) + bf2f(x2.x) + bf2f(x3.x);
        ay += bf2f(x0.y) + bf2f(x1.y) + bf2f(x2.y) + bf2f(x3.y);
        az += bf2f(x0.z) + bf2f(x1.z) + bf2f(x2.z) + bf2f(x3.z);
        aw += bf2f(x0.w) + bf2f(x1.w) + bf2f(x2.w) + bf2f(x3.w);
    }
    for (; j < end; ++j) {
        int e0 = elist[j];
        ushort4 x0 = *reinterpret_cast<const ushort4*>(Xe16 + (size_t)e0 * DD + lane * 4);
        ax += bf2f(x0.x); ay += bf2f(x0.y); az += bf2f(x0.z); aw += bf2f(x0.w);
    }
    float g = 1.0f + eps[0];
    ushort4 xp = *reinterpret_cast<const ushort4*>(Xp16 + (size_t)v * DD + lane * 4);
    float4 o;
    o.x = fmaf(g, bf2f(xp.x), ax);
    o.y = fmaf(g, bf2f(xp.y), ay);
    o.z = fmaf(g, bf2f(xp.z), az);
    o.w = fmaf(g, bf2f(xp.w), aw);
    float ss = o.x * o.x + o.y * o.y + o.z * o.z + o.w * o.w;
    #pragma unroll
    for (int off = 1; off < 32; off <<= 1) ss += __shfl_xor(ss, off, 64);
    float inv = 1.0f / fmaxf(sqrtf(ss), 1e-12f);
    o.x *= inv; o.y *= inv; o.z *= inv; o.w *= inv;
    *reinterpret_cast<float4*>(Out + (size_t)v * DD + lane * 4) = o;
}

extern "C" void kernel_launch(void* const* d_in, const int* in_sizes, int n_in,
                              void* d_out, int out_size, void* d_ws, size_t ws_size,
                              hipStream_t stream) {
    const float* X      = (const float*)d_in[0];
    const float* W      = (const float*)d_in[1];
    const float* eps    = (const float*)d_in[2];
    const int*   vertex = (const int*)d_in[3];
    const int*   edges  = (const int*)d_in[4];

    float* out = (float*)d_out;                 // [N,D]
    float* Xe  = out + (size_t)NN * DD;         // [E,D]

    // workspace layout (52.4 MB)
    ushort* Xp16 = (ushort*)d_ws;                        // N*D bf16
    ushort* Xe16 = Xp16 + (size_t)NN * DD;               // E*D bf16
    ushort* Wt16 = Xe16 + (size_t)NE * DD;               // D*D bf16 (transposed W)
    int*    ecnt = (int*)(Wt16 + DD * DD);               // E   (becomes cursor)
    int*    vcnt = ecnt + NE;                            // N   (becomes cursor)
    int*    eoff = vcnt + NN;                            // E+1
    int*    voff = eoff + NE + 1;                        // N+1
    int*    vlist = voff + NN + 1;                       // NNZ
    int*    elist = vlist + NNZP;                        // NNZ

    hipMemsetAsync(ecnt, 0, (size_t)(NE + NN) * sizeof(int), stream);

    convertWt<<<(DD * DD + 255) / 256, 256, 0, stream>>>(W, Wt16);
    gemm_mfma<<<(NN / 16 + 3) / 4, 256, 0, stream>>>(X, Wt16, Xp16);
    hist<<<(NNZP / 4 + 255) / 256, 256, 0, stream>>>(vertex, edges, ecnt, vcnt);
    scan2<<<2, 1024, 0, stream>>>(ecnt, eoff, vcnt, voff);
    place_binned<<<((NNZP + PCHUNK - 1) / PCHUNK) * 8, 256, 0, stream>>>(
        vertex, edges, ecnt, vcnt, vlist, elist);
    edge_gather<<<NE / 8, 256, 0, stream>>>(Xp16, eoff, vlist, Xe, Xe16);
    vertex_gather_out<<<NN / 8, 256, 0, stream>>>(Xp16, Xe16, voff, elist, eps, out);
}

// Round 5
// 422.844 us; speedup vs baseline: 13.1711x; 1.4965x over previous
//
#include <hip/hip_runtime.h>
#include <hip/hip_bf16.h>

#define NN   100000
#define NE   50000
#define NNZP 1600000
#define DD   128
#define NXCD 8
#define EBIN (NE / NXCD)     // 6250
#define VBIN (NN / NXCD)     // 12500

#define SCAN_TOT (NE + NN)                      // 150000 (ecnt|vcnt concatenated)
#define SCB      1024                           // elements per scan block
#define SCAN_NB  ((SCAN_TOT + SCB - 1) / SCB)   // 147

typedef __attribute__((ext_vector_type(8))) short bf16x8;
typedef __attribute__((ext_vector_type(4))) float f32x4;

__device__ __forceinline__ ushort f2bf(float f) {
    __hip_bfloat16 h = __float2bfloat16(f);
    return *reinterpret_cast<ushort*>(&h);
}
__device__ __forceinline__ float bf2f(ushort u) {
    union { unsigned int i; float f; } x; x.i = ((unsigned int)u) << 16; return x.f;
}

// ---------------- K0: Wt16[n][k] = bf16(W[k][n]) ----------------
__global__ __launch_bounds__(256) void convertWt(const float* __restrict__ W,
                                                 ushort* __restrict__ Wt) {
    int i = blockIdx.x * 256 + threadIdx.x;
    if (i >= DD * DD) return;
    int k = i >> 7, n = i & 127;
    Wt[n * DD + k] = f2bf(W[i]);
}

// ---------------- K1: Xp16 = bf16( X @ W ) via MFMA ----------------
__global__ __launch_bounds__(256) void gemm_mfma(const float* __restrict__ X,
                                                 const ushort* __restrict__ Wt,
                                                 ushort* __restrict__ Xp16) {
    __shared__ char WtL[DD * DD * 2];   // 32 KB, XOR-swizzled 16B chunks
    for (int c = threadIdx.x; c < 2048; c += 256) {
        int n = c >> 4, kc = c & 15;
        int dst = (n * 256 + kc * 16) ^ ((n & 7) << 4);
        *reinterpret_cast<int4*>(WtL + dst) = reinterpret_cast<const int4*>(Wt)[c];
    }
    __syncthreads();
    int wave = threadIdx.x >> 6;
    int lane = threadIdx.x & 63;
    int rowTile = blockIdx.x * 4 + wave;
    if (rowTile >= NN / 16) return;
    int r = lane & 15, half = lane >> 4;
    const float* xrow = X + (size_t)(rowTile * 16 + r) * DD;
    f32x4 acc[8];
    #pragma unroll
    for (int nt = 0; nt < 8; ++nt) acc[nt] = (f32x4)(0.f);
    #pragma unroll
    for (int kk = 0; kk < DD; kk += 32) {
        int kbase = kk + half * 8;
        float4 xa = *reinterpret_cast<const float4*>(xrow + kbase);
        float4 xb = *reinterpret_cast<const float4*>(xrow + kbase + 4);
        bf16x8 a;
        a[0] = (short)f2bf(xa.x); a[1] = (short)f2bf(xa.y);
        a[2] = (short)f2bf(xa.z); a[3] = (short)f2bf(xa.w);
        a[4] = (short)f2bf(xb.x); a[5] = (short)f2bf(xb.y);
        a[6] = (short)f2bf(xb.z); a[7] = (short)f2bf(xb.w);
        #pragma unroll
        for (int nt = 0; nt < 8; ++nt) {
            int n = nt * 16 + r;
            int off = (n * 256 + kbase * 2) ^ ((n & 7) << 4);
            bf16x8 b = *reinterpret_cast<const bf16x8*>(WtL + off);
            acc[nt] = __builtin_amdgcn_mfma_f32_16x16x32_bf16(a, b, acc[nt], 0, 0, 0);
        }
    }
    int row0 = rowTile * 16 + half * 4;   // C/D: col=lane&15, row=(lane>>4)*4+q
    #pragma unroll
    for (int nt = 0; nt < 8; ++nt)
        #pragma unroll
        for (int q = 0; q < 4; ++q)
            Xp16[(size_t)(row0 + q) * DD + nt * 16 + r] = f2bf(acc[nt][q]);
}

// ---------------- K2: degree histograms ----------------
__global__ __launch_bounds__(256) void hist(const int* __restrict__ vertex,
                                            const int* __restrict__ edges,
                                            int* __restrict__ ecnt,
                                            int* __restrict__ vcnt) {
    int i0 = (blockIdx.x * 256 + threadIdx.x) * 4;
    if (i0 >= NNZP) return;
    int4 e4 = *reinterpret_cast<const int4*>(edges + i0);
    int4 v4 = *reinterpret_cast<const int4*>(vertex + i0);
    atomicAdd(&ecnt[e4.x], 1); atomicAdd(&ecnt[e4.y], 1);
    atomicAdd(&ecnt[e4.z], 1); atomicAdd(&ecnt[e4.w], 1);
    atomicAdd(&vcnt[v4.x], 1); atomicAdd(&vcnt[v4.y], 1);
    atomicAdd(&vcnt[v4.z], 1); atomicAdd(&vcnt[v4.w], 1);
}

// ------- K3a: per-block sums of combined [ecnt|vcnt] (SCB elems/block) -------
__global__ __launch_bounds__(256) void scan_partial(const int* __restrict__ cnt,
                                                    int* __restrict__ bsum) {
    int t = threadIdx.x;
    int idx = blockIdx.x * SCB + t * 4;
    int s = 0;
    if (idx + 3 < SCAN_TOT) {
        int4 c = *reinterpret_cast<const int4*>(cnt + idx);
        s = c.x + c.y + c.z + c.w;
    } else {
        for (int k = 0; k < 4; ++k) if (idx + k < SCAN_TOT) s += cnt[idx + k];
    }
    #pragma unroll
    for (int off = 1; off < 64; off <<= 1) s += __shfl_xor(s, off, 64);
    __shared__ int ws[4];
    if ((t & 63) == 0) ws[t >> 6] = s;
    __syncthreads();
    if (t == 0) bsum[blockIdx.x] = ws[0] + ws[1] + ws[2] + ws[3];
}

// ------- K3b: exclusive scan of the 147 block sums; fixed tails -------
__global__ __launch_bounds__(256) void scan_bsum(const int* __restrict__ bsum,
                                                 int* __restrict__ boff,
                                                 int* __restrict__ eoff,
                                                 int* __restrict__ voff) {
    __shared__ int sh[256];
    int t = threadIdx.x;
    int v = (t < SCAN_NB) ? bsum[t] : 0;
    sh[t] = v;
    __syncthreads();
    for (int d = 1; d < 256; d <<= 1) {
        int x = (t >= d) ? sh[t - d] : 0;
        __syncthreads();
        sh[t] += x;
        __syncthreads();
    }
    if (t < SCAN_NB) boff[t] = sh[t] - v;
    if (t == 0) { eoff[NE] = NNZP; voff[NN] = NNZP; }
}

// ------- K3c: final scan: write eoff/voff and cursors into cnt -------
__global__ __launch_bounds__(256) void scan_final(int* __restrict__ cnt,
                                                  const int* __restrict__ boff,
                                                  int* __restrict__ eoff,
                                                  int* __restrict__ voff) {
    int t = threadIdx.x;
    int idx = blockIdx.x * SCB + t * 4;
    int c0 = 0, c1 = 0, c2 = 0, c3 = 0;
    if (idx + 3 < SCAN_TOT) {
        int4 c = *reinterpret_cast<const int4*>(cnt + idx);
        c0 = c.x; c1 = c.y; c2 = c.z; c3 = c.w;
    } else if (idx < SCAN_TOT) {
        c0 = cnt[idx];
        if (idx + 1 < SCAN_TOT) c1 = cnt[idx + 1];
        if (idx + 2 < SCAN_TOT) c2 = cnt[idx + 2];
    }
    int tsum = c0 + c1 + c2 + c3;
    int inc = tsum;
    #pragma unroll
    for (int d = 1; d < 64; d <<= 1) {
        int x = __shfl_up(inc, d, 64);
        if ((t & 63) >= d) inc += x;
    }
    int wexc = inc - tsum;
    __shared__ int wsum[4];
    if ((t & 63) == 63) wsum[t >> 6] = inc;
    __syncthreads();
    int wid = t >> 6, wbase = 0;
    #pragma unroll
    for (int w = 0; w < 3; ++w) if (w < wid) wbase += wsum[w];
    int base = boff[blockIdx.x] + wbase + wexc;
    int s0 = base, s1 = s0 + c0, s2 = s1 + c1, s3 = s2 + c2;
    #define WR(K, SV) do { int i = idx + (K); if (i < SCAN_TOT) {            \
        int adj = (i < NE) ? (SV) : (SV) - NNZP;                             \
        if (i < NE) eoff[i] = adj; else voff[i - NE] = adj;                  \
        cnt[i] = adj; } } while (0)
    WR(0, s0); WR(1, s1); WR(2, s2); WR(3, s3);
    #undef WR
}

// ---------------- K4: XCD-binned placement ----------------
#define PCHUNK 4096
__global__ __launch_bounds__(256) void place_binned(const int* __restrict__ vertex,
                                                    const int* __restrict__ edges,
                                                    int* __restrict__ ecur,
                                                    int* __restrict__ vcur,
                                                    int* __restrict__ vlist,
                                                    int* __restrict__ elist) {
    int xcd   = blockIdx.x & 7;
    int chunk = blockIdx.x >> 3;
    int base  = chunk * PCHUNK;
    int end   = base + PCHUNK; if (end > NNZP) end = NNZP;
    const int elo = xcd * EBIN, ehi = elo + EBIN;
    const int vlo = xcd * VBIN, vhi = vlo + VBIN;
    for (int i = base + threadIdx.x * 4; i + 3 < end; i += 1024) {
        int4 vv = *reinterpret_cast<const int4*>(vertex + i);
        int4 ee = *reinterpret_cast<const int4*>(edges + i);
        #define PLACE1(E, V)                                                  \
            if ((E) >= elo && (E) < ehi) vlist[atomicAdd(&ecur[E], 1)] = (V); \
            if ((V) >= vlo && (V) < vhi) elist[atomicAdd(&vcur[V], 1)] = (E);
        PLACE1(ee.x, vv.x) PLACE1(ee.y, vv.y) PLACE1(ee.z, vv.z) PLACE1(ee.w, vv.w)
        #undef PLACE1
    }
}

// ---------------- K5: Xe[e] = mean of Xp16 rows; also Xe16 ----------------
__global__ __launch_bounds__(256) void edge_gather(const ushort* __restrict__ Xp16,
                                                   const int* __restrict__ eoff,
                                                   const int* __restrict__ vlist,
                                                   float* __restrict__ Xe,
                                                   ushort* __restrict__ Xe16) {
    int e = blockIdx.x * 8 + (threadIdx.x >> 5);
    if (e >= NE) return;
    int lane = threadIdx.x & 31;
    int start = eoff[e], end = eoff[e + 1];
    float ax = 0.f, ay = 0.f, az = 0.f, aw = 0.f;
    int j = start;
    for (; j + 3 < end; j += 4) {
        int v0 = vlist[j], v1 = vlist[j + 1], v2 = vlist[j + 2], v3 = vlist[j + 3];
        ushort4 x0 = *reinterpret_cast<const ushort4*>(Xp16 + (size_t)v0 * DD + lane * 4);
        ushort4 x1 = *reinterpret_cast<const ushort4*>(Xp16 + (size_t)v1 * DD + lane * 4);
        ushort4 x2 = *reinterpret_cast<const ushort4*>(Xp16 + (size_t)v2 * DD + lane * 4);
        ushort4 x3 = *reinterpret_cast<const ushort4*>(Xp16 + (size_t)v3 * DD + lane * 4);
        ax += bf2f(x0.x) + bf2f(x1.x) + bf2f(x2.x) + bf2f(x3.x);
        ay += bf2f(x0.y) + bf2f(x1.y) + bf2f(x2.y) + bf2f(x3.y);
        az += bf2f(x0.z) + bf2f(x1.z) + bf2f(x2.z) + bf2f(x3.z);
        aw += bf2f(x0.w) + bf2f(x1.w) + bf2f(x2.w) + bf2f(x3.w);
    }
    for (; j < end; ++j) {
        int v0 = vlist[j];
        ushort4 x0 = *reinterpret_cast<const ushort4*>(Xp16 + (size_t)v0 * DD + lane * 4);
        ax += bf2f(x0.x); ay += bf2f(x0.y); az += bf2f(x0.z); aw += bf2f(x0.w);
    }
    float inv = 1.0f / fmaxf((float)(end - start), 1.0f);
    float4 o = make_float4(ax * inv, ay * inv, az * inv, aw * inv);
    *reinterpret_cast<float4*>(Xe + (size_t)e * DD + lane * 4) = o;
    ushort4 h;
    h.x = f2bf(o.x); h.y = f2bf(o.y); h.z = f2bf(o.z); h.w = f2bf(o.w);
    *reinterpret_cast<ushort4*>(Xe16 + (size_t)e * DD + lane * 4) = h;
}

// -------- K6: Xv = sum Xe16 rows; out = normalize((1+eps)*Xp + Xv) --------
__global__ __launch_bounds__(256) void vertex_gather_out(const ushort* __restrict__ Xp16,
                                                         const ushort* __restrict__ Xe16,
                                                         const int* __restrict__ voff,
                                                         const int* __restrict__ elist,
                                                         const float* __restrict__ eps,
                                                         float* __restrict__ Out) {
    int v = blockIdx.x * 8 + (threadIdx.x >> 5);
    if (v >= NN) return;
    int lane = threadIdx.x & 31;
    int start = voff[v], end = voff[v + 1];
    float ax = 0.f, ay = 0.f, az = 0.f, aw = 0.f;
    int j = start;
    for (; j + 3 < end; j += 4) {
        int e0 = elist[j], e1 = elist[j + 1], e2 = elist[j + 2], e3 = elist[j + 3];
        ushort4 x0 = *reinterpret_cast<const ushort4*>(Xe16 + (size_t)e0 * DD + lane * 4);
        ushort4 x1 = *reinterpret_cast<const ushort4*>(Xe16 + (size_t)e1 * DD + lane * 4);
        ushort4 x2 = *reinterpret_cast<const ushort4*>(Xe16 + (size_t)e2 * DD + lane * 4);
        ushort4 x3 = *reinterpret_cast<const ushort4*>(Xe16 + (size_t)e3 * DD + lane * 4);
        ax += bf2f(x0.x) + bf2f(x1.x) + bf2f(x2.x) + bf2f(x3.x);
        ay += bf2f(x0.y) + bf2f(x1.y) + bf2f(x2.y) + bf2f(x3.y);
        az += bf2f(x0.z) + bf2f(x1.z) + bf2f(x2.z) + bf2f(x3.z);
        aw += bf2f(x0.w) + bf2f(x1.w) + bf2f(x2.w) + bf2f(x3.w);
    }
    for (; j < end; ++j) {
        int e0 = elist[j];
        ushort4 x0 = *reinterpret_cast<const ushort4*>(Xe16 + (size_t)e0 * DD + lane * 4);
        ax += bf2f(x0.x); ay += bf2f(x0.y); az += bf2f(x0.z); aw += bf2f(x0.w);
    }
    float g = 1.0f + eps[0];
    ushort4 xp = *reinterpret_cast<const ushort4*>(Xp16 + (size_t)v * DD + lane * 4);
    float4 o;
    o.x = fmaf(g, bf2f(xp.x), ax);
    o.y = fmaf(g, bf2f(xp.y), ay);
    o.z = fmaf(g, bf2f(xp.z), az);
    o.w = fmaf(g, bf2f(xp.w), aw);
    float ss = o.x * o.x + o.y * o.y + o.z * o.z + o.w * o.w;
    #pragma unroll
    for (int off = 1; off < 32; off <<= 1) ss += __shfl_xor(ss, off, 64);
    float inv = 1.0f / fmaxf(sqrtf(ss), 1e-12f);
    o.x *= inv; o.y *= inv; o.z *= inv; o.w *= inv;
    *reinterpret_cast<float4*>(Out + (size_t)v * DD + lane * 4) = o;
}

extern "C" void kernel_launch(void* const* d_in, const int* in_sizes, int n_in,
                              void* d_out, int out_size, void* d_ws, size_t ws_size,
                              hipStream_t stream) {
    const float* X      = (const float*)d_in[0];
    const float* W      = (const float*)d_in[1];
    const float* eps    = (const float*)d_in[2];
    const int*   vertex = (const int*)d_in[3];
    const int*   edges  = (const int*)d_in[4];

    float* out = (float*)d_out;                 // [N,D]
    float* Xe  = out + (size_t)NN * DD;         // [E,D]

    // workspace layout (~53 MB)
    ushort* Xp16 = (ushort*)d_ws;                        // N*D bf16
    ushort* Xe16 = Xp16 + (size_t)NN * DD;               // E*D bf16
    ushort* Wt16 = Xe16 + (size_t)NE * DD;               // D*D bf16
    int*    ecnt = (int*)(Wt16 + DD * DD);               // E   (becomes cursor)
    int*    vcnt = ecnt + NE;                            // N   (becomes cursor) — contiguous with ecnt
    int*    eoff = vcnt + NN;                            // E+1
    int*    voff = eoff + NE + 1;                        // N+1
    int*    vlist = voff + NN + 1;                       // NNZ
    int*    elist = vlist + NNZP;                        // NNZ
    int*    bsum  = elist + NNZP;                        // SCAN_NB
    int*    boff  = bsum + SCAN_NB;                      // SCAN_NB

    hipMemsetAsync(ecnt, 0, (size_t)(NE + NN) * sizeof(int), stream);

    convertWt<<<(DD * DD + 255) / 256, 256, 0, stream>>>(W, Wt16);
    gemm_mfma<<<(NN / 16 + 3) / 4, 256, 0, stream>>>(X, Wt16, Xp16);
    hist<<<(NNZP / 4 + 255) / 256, 256, 0, stream>>>(vertex, edges, ecnt, vcnt);
    scan_partial<<<SCAN_NB, 256, 0, stream>>>(ecnt, bsum);
    scan_bsum<<<1, 256, 0, stream>>>(bsum, boff, eoff, voff);
    scan_final<<<SCAN_NB, 256, 0, stream>>>(ecnt, boff, eoff, voff);
    place_binned<<<((NNZP + PCHUNK - 1) / PCHUNK) * 8, 256, 0, stream>>>(
        vertex, edges, ecnt, vcnt, vlist, elist);
    edge_gather<<<NE / 8, 256, 0, stream>>>(Xp16, eoff, vlist, Xe, Xe16);
    vertex_gather_out<<<NN / 8, 256, 0, stream>>>(Xp16, Xe16, voff, elist, eps, out);
}

// Round 6
// 365.020 us; speedup vs baseline: 15.2576x; 1.1584x over previous
//
#include <hip/hip_runtime.h>
#include <hip/hip_bf16.h>

#define NN   100000
#define NE   50000
#define NNZP 1600000
#define DD   128

#define SCAN_TOT (NE + NN)                      // 150000 (ecnt|vcnt concatenated)
#define SCB      1024
#define SCAN_NB  ((SCAN_TOT + SCB - 1) / SCB)   // 147

#define EBK  512
#define NBE  ((NE + EBK - 1) / EBK)             // 98
#define VBK  512
#define NBV  ((NN + VBK - 1) / VBK)             // 196
#define CH   2048                               // pairs per bucket_scatter block

typedef __attribute__((ext_vector_type(8))) short bf16x8;
typedef __attribute__((ext_vector_type(4))) float f32x4;

__device__ __forceinline__ ushort f2bf(float f) {
    __hip_bfloat16 h = __float2bfloat16(f);
    return *reinterpret_cast<ushort*>(&h);
}
__device__ __forceinline__ float bf2f(ushort u) {
    union { unsigned int i; float f; } x; x.i = ((unsigned int)u) << 16; return x.f;
}

// ---------------- K0: Wt16[n][k] = bf16(W[k][n]) ----------------
__global__ __launch_bounds__(256) void convertWt(const float* __restrict__ W,
                                                 ushort* __restrict__ Wt) {
    int i = blockIdx.x * 256 + threadIdx.x;
    if (i >= DD * DD) return;
    int k = i >> 7, n = i & 127;
    Wt[n * DD + k] = f2bf(W[i]);
}

// ---------------- K1: Xp16 = bf16( X @ W ) via MFMA ----------------
__global__ __launch_bounds__(256) void gemm_mfma(const float* __restrict__ X,
                                                 const ushort* __restrict__ Wt,
                                                 ushort* __restrict__ Xp16) {
    __shared__ char WtL[DD * DD * 2];   // 32 KB, XOR-swizzled 16B chunks
    for (int c = threadIdx.x; c < 2048; c += 256) {
        int n = c >> 4, kc = c & 15;
        int dst = (n * 256 + kc * 16) ^ ((n & 7) << 4);
        *reinterpret_cast<int4*>(WtL + dst) = reinterpret_cast<const int4*>(Wt)[c];
    }
    __syncthreads();
    int wave = threadIdx.x >> 6;
    int lane = threadIdx.x & 63;
    int rowTile = blockIdx.x * 4 + wave;
    if (rowTile >= NN / 16) return;
    int r = lane & 15, half = lane >> 4;
    const float* xrow = X + (size_t)(rowTile * 16 + r) * DD;
    f32x4 acc[8];
    #pragma unroll
    for (int nt = 0; nt < 8; ++nt) acc[nt] = (f32x4)(0.f);
    #pragma unroll
    for (int kk = 0; kk < DD; kk += 32) {
        int kbase = kk + half * 8;
        float4 xa = *reinterpret_cast<const float4*>(xrow + kbase);
        float4 xb = *reinterpret_cast<const float4*>(xrow + kbase + 4);
        bf16x8 a;
        a[0] = (short)f2bf(xa.x); a[1] = (short)f2bf(xa.y);
        a[2] = (short)f2bf(xa.z); a[3] = (short)f2bf(xa.w);
        a[4] = (short)f2bf(xb.x); a[5] = (short)f2bf(xb.y);
        a[6] = (short)f2bf(xb.z); a[7] = (short)f2bf(xb.w);
        #pragma unroll
        for (int nt = 0; nt < 8; ++nt) {
            int n = nt * 16 + r;
            int off = (n * 256 + kbase * 2) ^ ((n & 7) << 4);
            bf16x8 b = *reinterpret_cast<const bf16x8*>(WtL + off);
            acc[nt] = __builtin_amdgcn_mfma_f32_16x16x32_bf16(a, b, acc[nt], 0, 0, 0);
        }
    }
    int row0 = rowTile * 16 + half * 4;   // C/D: col=lane&15, row=(lane>>4)*4+q
    #pragma unroll
    for (int nt = 0; nt < 8; ++nt)
        #pragma unroll
        for (int q = 0; q < 4; ++q)
            Xp16[(size_t)(row0 + q) * DD + nt * 16 + r] = f2bf(acc[nt][q]);
}

// ---------------- K2: degree histograms ----------------
__global__ __launch_bounds__(256) void hist(const int* __restrict__ vertex,
                                            const int* __restrict__ edges,
                                            int* __restrict__ ecnt,
                                            int* __restrict__ vcnt) {
    int i0 = (blockIdx.x * 256 + threadIdx.x) * 4;
    if (i0 >= NNZP) return;
    int4 e4 = *reinterpret_cast<const int4*>(edges + i0);
    int4 v4 = *reinterpret_cast<const int4*>(vertex + i0);
    atomicAdd(&ecnt[e4.x], 1); atomicAdd(&ecnt[e4.y], 1);
    atomicAdd(&ecnt[e4.z], 1); atomicAdd(&ecnt[e4.w], 1);
    atomicAdd(&vcnt[v4.x], 1); atomicAdd(&vcnt[v4.y], 1);
    atomicAdd(&vcnt[v4.z], 1); atomicAdd(&vcnt[v4.w], 1);
}

// ------- K3a: per-block sums of combined [ecnt|vcnt] -------
__global__ __launch_bounds__(256) void scan_partial(const int* __restrict__ cnt,
                                                    int* __restrict__ bsum) {
    int t = threadIdx.x;
    int idx = blockIdx.x * SCB + t * 4;
    int s = 0;
    if (idx + 3 < SCAN_TOT) {
        int4 c = *reinterpret_cast<const int4*>(cnt + idx);
        s = c.x + c.y + c.z + c.w;
    } else {
        for (int k = 0; k < 4; ++k) if (idx + k < SCAN_TOT) s += cnt[idx + k];
    }
    #pragma unroll
    for (int off = 1; off < 64; off <<= 1) s += __shfl_xor(s, off, 64);
    __shared__ int ws[4];
    if ((t & 63) == 0) ws[t >> 6] = s;
    __syncthreads();
    if (t == 0) bsum[blockIdx.x] = ws[0] + ws[1] + ws[2] + ws[3];
}

// ------- K3b: exclusive scan of the 147 block sums; fixed tails -------
__global__ __launch_bounds__(256) void scan_bsum(const int* __restrict__ bsum,
                                                 int* __restrict__ boff,
                                                 int* __restrict__ eoff,
                                                 int* __restrict__ voff) {
    __shared__ int sh[256];
    int t = threadIdx.x;
    int v = (t < SCAN_NB) ? bsum[t] : 0;
    sh[t] = v;
    __syncthreads();
    for (int d = 1; d < 256; d <<= 1) {
        int x = (t >= d) ? sh[t - d] : 0;
        __syncthreads();
        sh[t] += x;
        __syncthreads();
    }
    if (t < SCAN_NB) boff[t] = sh[t] - v;
    if (t == 0) { eoff[NE] = NNZP; voff[NN] = NNZP; }
}

// ------- K3c: final scan: write eoff/voff -------
__global__ __launch_bounds__(256) void scan_final(int* __restrict__ cnt,
                                                  const int* __restrict__ boff,
                                                  int* __restrict__ eoff,
                                                  int* __restrict__ voff) {
    int t = threadIdx.x;
    int idx = blockIdx.x * SCB + t * 4;
    int c0 = 0, c1 = 0, c2 = 0, c3 = 0;
    if (idx + 3 < SCAN_TOT) {
        int4 c = *reinterpret_cast<const int4*>(cnt + idx);
        c0 = c.x; c1 = c.y; c2 = c.z; c3 = c.w;
    } else if (idx < SCAN_TOT) {
        c0 = cnt[idx];
        if (idx + 1 < SCAN_TOT) c1 = cnt[idx + 1];
        if (idx + 2 < SCAN_TOT) c2 = cnt[idx + 2];
    }
    int tsum = c0 + c1 + c2 + c3;
    int inc = tsum;
    #pragma unroll
    for (int d = 1; d < 64; d <<= 1) {
        int x = __shfl_up(inc, d, 64);
        if ((t & 63) >= d) inc += x;
    }
    int wexc = inc - tsum;
    __shared__ int wsum[4];
    if ((t & 63) == 63) wsum[t >> 6] = inc;
    __syncthreads();
    int wid = t >> 6, wbase = 0;
    #pragma unroll
    for (int w = 0; w < 3; ++w) if (w < wid) wbase += wsum[w];
    int base = boff[blockIdx.x] + wbase + wexc;
    int s0 = base, s1 = s0 + c0, s2 = s1 + c1, s3 = s2 + c2;
    #define WR(K, SV) do { int i = idx + (K); if (i < SCAN_TOT) {            \
        int adj = (i < NE) ? (SV) : (SV) - NNZP;                             \
        if (i < NE) eoff[i] = adj; else voff[i - NE] = adj; } } while (0)
    WR(0, s0); WR(1, s1); WR(2, s2); WR(3, s3);
    #undef WR
}

// ------- K3d: init per-bucket global cursors from eoff/voff -------
__global__ __launch_bounds__(256) void init_bcur(const int* __restrict__ eoff,
                                                 const int* __restrict__ voff,
                                                 int* __restrict__ gEcur,
                                                 int* __restrict__ gVcur) {
    int t = threadIdx.x;
    if (t < NBE) gEcur[t] = eoff[t * EBK];
    if (t < NBV) gVcur[t] = voff[t * VBK];
}

// ------- K4a: bucket both directions; block-contiguous runs -> coalesced writes ----
__global__ __launch_bounds__(256) void bucket_scatter(const int* __restrict__ vertex,
                                                      const int* __restrict__ edges,
                                                      int* __restrict__ gEcur,
                                                      int* __restrict__ gVcur,
                                                      int2* __restrict__ ebuck,
                                                      int2* __restrict__ vbuck) {
    __shared__ int cE[NBE], bE[NBE], cV[NBV], bV[NBV];
    const int t = threadIdx.x;
    for (int i = t; i < NBE; i += 256) cE[i] = 0;
    for (int i = t; i < NBV; i += 256) cV[i] = 0;
    __syncthreads();
    const int base = blockIdx.x * CH;
    int e[8], v[8];
    #pragma unroll
    for (int k = 0; k < 8; ++k) {
        int idx = base + k * 256 + t;
        if (idx < NNZP) {
            e[k] = edges[idx]; v[k] = vertex[idx];
            atomicAdd(&cE[e[k] >> 9], 1);
            atomicAdd(&cV[v[k] >> 9], 1);
        } else e[k] = -1;
    }
    __syncthreads();
    for (int i = t; i < NBE; i += 256) {
        int c = cE[i];
        bE[i] = c ? atomicAdd(&gEcur[i], c) : 0;
        cE[i] = 0;
    }
    for (int i = t; i < NBV; i += 256) {
        int c = cV[i];
        bV[i] = c ? atomicAdd(&gVcur[i], c) : 0;
        cV[i] = 0;
    }
    __syncthreads();
    #pragma unroll
    for (int k = 0; k < 8; ++k) {
        if (e[k] >= 0) {
            int be = e[k] >> 9, bv = v[k] >> 9;
            int pe = bE[be] + atomicAdd(&cE[be], 1);
            ebuck[pe] = make_int2(e[k], v[k]);
            int pv = bV[bv] + atomicAdd(&cV[bv], 1);
            vbuck[pv] = make_int2(v[k], e[k]);
        }
    }
}

// ------- K4b: one block per bucket: place payloads at final CSR slots (LDS cursors) ----
__global__ __launch_bounds__(256) void place_buckets(const int2* __restrict__ ebuck,
                                                     const int2* __restrict__ vbuck,
                                                     const int* __restrict__ eoff,
                                                     const int* __restrict__ voff,
                                                     int* __restrict__ vlist,
                                                     int* __restrict__ elist) {
    __shared__ int cur[EBK];
    const int t = threadIdx.x;
    int b = blockIdx.x;
    if (b < NBE) {
        int e0 = b * EBK;
        int nseg = min(EBK, NE - e0);
        for (int i = t; i < nseg; i += 256) cur[i] = eoff[e0 + i];
        __syncthreads();
        int start = eoff[e0], end = eoff[min(e0 + EBK, NE)];
        for (int i = start + t; i < end; i += 256) {
            int2 p = ebuck[i];
            vlist[atomicAdd(&cur[p.x - e0], 1)] = p.y;
        }
    } else {
        b -= NBE;
        int v0 = b * VBK;
        int nseg = min(VBK, NN - v0);
        for (int i = t; i < nseg; i += 256) cur[i] = voff[v0 + i];
        __syncthreads();
        int start = voff[v0], end = voff[min(v0 + VBK, NN)];
        for (int i = start + t; i < end; i += 256) {
            int2 p = vbuck[i];
            elist[atomicAdd(&cur[p.x - v0], 1)] = p.y;
        }
    }
}

// ---------------- K5: Xe[e] = mean of Xp16 rows; also Xe16 ----------------
__global__ __launch_bounds__(256) void edge_gather(const ushort* __restrict__ Xp16,
                                                   const int* __restrict__ eoff,
                                                   const int* __restrict__ vlist,
                                                   float* __restrict__ Xe,
                                                   ushort* __restrict__ Xe16) {
    int e = blockIdx.x * 8 + (threadIdx.x >> 5);
    if (e >= NE) return;
    int lane = threadIdx.x & 31;
    int start = eoff[e], end = eoff[e + 1];
    float ax = 0.f, ay = 0.f, az = 0.f, aw = 0.f;
    int j = start;
    for (; j + 3 < end; j += 4) {
        int v0 = vlist[j], v1 = vlist[j + 1], v2 = vlist[j + 2], v3 = vlist[j + 3];
        ushort4 x0 = *reinterpret_cast<const ushort4*>(Xp16 + (size_t)v0 * DD + lane * 4);
        ushort4 x1 = *reinterpret_cast<const ushort4*>(Xp16 + (size_t)v1 * DD + lane * 4);
        ushort4 x2 = *reinterpret_cast<const ushort4*>(Xp16 + (size_t)v2 * DD + lane * 4);
        ushort4 x3 = *reinterpret_cast<const ushort4*>(Xp16 + (size_t)v3 * DD + lane * 4);
        ax += bf2f(x0.x) + bf2f(x1.x) + bf2f(x2.x) + bf2f(x3.x);
        ay += bf2f(x0.y) + bf2f(x1.y) + bf2f(x2.y) + bf2f(x3.y);
        az += bf2f(x0.z) + bf2f(x1.z) + bf2f(x2.z) + bf2f(x3.z);
        aw += bf2f(x0.w) + bf2f(x1.w) + bf2f(x2.w) + bf2f(x3.w);
    }
    for (; j < end; ++j) {
        int v0 = vlist[j];
        ushort4 x0 = *reinterpret_cast<const ushort4*>(Xp16 + (size_t)v0 * DD + lane * 4);
        ax += bf2f(x0.x); ay += bf2f(x0.y); az += bf2f(x0.z); aw += bf2f(x0.w);
    }
    float inv = 1.0f / fmaxf((float)(end - start), 1.0f);
    float4 o = make_float4(ax * inv, ay * inv, az * inv, aw * inv);
    *reinterpret_cast<float4*>(Xe + (size_t)e * DD + lane * 4) = o;
    ushort4 h;
    h.x = f2bf(o.x); h.y = f2bf(o.y); h.z = f2bf(o.z); h.w = f2bf(o.w);
    *reinterpret_cast<ushort4*>(Xe16 + (size_t)e * DD + lane * 4) = h;
}

// -------- K6: Xv = sum Xe16 rows; out = normalize((1+eps)*Xp + Xv) --------
__global__ __launch_bounds__(256) void vertex_gather_out(const ushort* __restrict__ Xp16,
                                                         const ushort* __restrict__ Xe16,
                                                         const int* __restrict__ voff,
                                                         const int* __restrict__ elist,
                                                         const float* __restrict__ eps,
                                                         float* __restrict__ Out) {
    int v = blockIdx.x * 8 + (threadIdx.x >> 5);
    if (v >= NN) return;
    int lane = threadIdx.x & 31;
    int start = voff[v], end = voff[v + 1];
    float ax = 0.f, ay = 0.f, az = 0.f, aw = 0.f;
    int j = start;
    for (; j + 3 < end; j += 4) {
        int e0 = elist[j], e1 = elist[j + 1], e2 = elist[j + 2], e3 = elist[j + 3];
        ushort4 x0 = *reinterpret_cast<const ushort4*>(Xe16 + (size_t)e0 * DD + lane * 4);
        ushort4 x1 = *reinterpret_cast<const ushort4*>(Xe16 + (size_t)e1 * DD + lane * 4);
        ushort4 x2 = *reinterpret_cast<const ushort4*>(Xe16 + (size_t)e2 * DD + lane * 4);
        ushort4 x3 = *reinterpret_cast<const ushort4*>(Xe16 + (size_t)e3 * DD + lane * 4);
        ax += bf2f(x0.x) + bf2f(x1.x) + bf2f(x2.x) + bf2f(x3.x);
        ay += bf2f(x0.y) + bf2f(x1.y) + bf2f(x2.y) + bf2f(x3.y);
        az += bf2f(x0.z) + bf2f(x1.z) + bf2f(x2.z) + bf2f(x3.z);
        aw += bf2f(x0.w) + bf2f(x1.w) + bf2f(x2.w) + bf2f(x3.w);
    }
    for (; j < end; ++j) {
        int e0 = elist[j];
        ushort4 x0 = *reinterpret_cast<const ushort4*>(Xe16 + (size_t)e0 * DD + lane * 4);
        ax += bf2f(x0.x); ay += bf2f(x0.y); az += bf2f(x0.z); aw += bf2f(x0.w);
    }
    float g = 1.0f + eps[0];
    ushort4 xp = *reinterpret_cast<const ushort4*>(Xp16 + (size_t)v * DD + lane * 4);
    float4 o;
    o.x = fmaf(g, bf2f(xp.x), ax);
    o.y = fmaf(g, bf2f(xp.y), ay);
    o.z = fmaf(g, bf2f(xp.z), az);
    o.w = fmaf(g, bf2f(xp.w), aw);
    float ss = o.x * o.x + o.y * o.y + o.z * o.z + o.w * o.w;
    #pragma unroll
    for (int off = 1; off < 32; off <<= 1) ss += __shfl_xor(ss, off, 64);
    float inv = 1.0f / fmaxf(sqrtf(ss), 1e-12f);
    o.x *= inv; o.y *= inv; o.z *= inv; o.w *= inv;
    *reinterpret_cast<float4*>(Out + (size_t)v * DD + lane * 4) = o;
}

extern "C" void kernel_launch(void* const* d_in, const int* in_sizes, int n_in,
                              void* d_out, int out_size, void* d_ws, size_t ws_size,
                              hipStream_t stream) {
    const float* X      = (const float*)d_in[0];
    const float* W      = (const float*)d_in[1];
    const float* eps    = (const float*)d_in[2];
    const int*   vertex = (const int*)d_in[3];
    const int*   edges  = (const int*)d_in[4];

    float* out = (float*)d_out;                 // [N,D] — scratch for buckets until K6
    float* Xe  = out + (size_t)NN * DD;         // [E,D]

    // bucket arrays live in the 'out' region (dead until vertex_gather_out rewrites it)
    int2* ebuck = (int2*)out;                   // NNZ int2 = 12.8 MB
    int2* vbuck = ebuck + NNZP;                 // NNZ int2 = 12.8 MB (total 25.6 <= 51.2)

    // workspace layout (~53 MB)
    ushort* Xp16 = (ushort*)d_ws;                        // N*D bf16
    ushort* Xe16 = Xp16 + (size_t)NN * DD;               // E*D bf16
    ushort* Wt16 = Xe16 + (size_t)NE * DD;               // D*D bf16
    int*    ecnt = (int*)(Wt16 + DD * DD);               // E
    int*    vcnt = ecnt + NE;                            // N (contiguous with ecnt)
    int*    eoff = vcnt + NN;                            // E+1
    int*    voff = eoff + NE + 1;                        // N+1
    int*    vlist = voff + NN + 1;                       // NNZ
    int*    elist = vlist + NNZP;                        // NNZ
    int*    bsum  = elist + NNZP;                        // SCAN_NB
    int*    boff  = bsum + SCAN_NB;                      // SCAN_NB
    int*    gEcur = boff + SCAN_NB;                      // NBE
    int*    gVcur = gEcur + NBE;                         // NBV

    hipMemsetAsync(ecnt, 0, (size_t)(NE + NN) * sizeof(int), stream);

    convertWt<<<(DD * DD + 255) / 256, 256, 0, stream>>>(W, Wt16);
    gemm_mfma<<<(NN / 16 + 3) / 4, 256, 0, stream>>>(X, Wt16, Xp16);
    hist<<<(NNZP / 4 + 255) / 256, 256, 0, stream>>>(vertex, edges, ecnt, vcnt);
    scan_partial<<<SCAN_NB, 256, 0, stream>>>(ecnt, bsum);
    scan_bsum<<<1, 256, 0, stream>>>(bsum, boff, eoff, voff);
    scan_final<<<SCAN_NB, 256, 0, stream>>>(ecnt, boff, eoff, voff);
    init_bcur<<<1, 256, 0, stream>>>(eoff, voff, gEcur, gVcur);
    bucket_scatter<<<(NNZP + CH - 1) / CH, 256, 0, stream>>>(
        vertex, edges, gEcur, gVcur, ebuck, vbuck);
    place_buckets<<<NBE + NBV, 256, 0, stream>>>(ebuck, vbuck, eoff, voff, vlist, elist);
    edge_gather<<<NE / 8, 256, 0, stream>>>(Xp16, eoff, vlist, Xe, Xe16);
    vertex_gather_out<<<NN / 8, 256, 0, stream>>>(Xp16, Xe16, voff, elist, eps, out);
}

// Round 7
// 266.729 us; speedup vs baseline: 20.8800x; 1.3685x over previous
//
#include <hip/hip_runtime.h>
#include <hip/hip_bf16.h>

#define NN   100000
#define NE   50000
#define NNZP 1600000
#define DD   128

#define EBK  512
#define NBE  ((NE + EBK - 1) / EBK)             // 98
#define VBK  512
#define NBV  ((NN + VBK - 1) / VBK)             // 196
#define NBT  (NBE + NBV)                        // 294
#define CH   2048                               // pairs per block
#define NCHB ((NNZP + CH - 1) / CH)             // 782

typedef __attribute__((ext_vector_type(8))) short bf16x8;
typedef __attribute__((ext_vector_type(4))) float f32x4;

__device__ __forceinline__ ushort f2bf(float f) {
    __hip_bfloat16 h = __float2bfloat16(f);
    return *reinterpret_cast<ushort*>(&h);
}
__device__ __forceinline__ float bf2f(ushort u) {
    union { unsigned int i; float f; } x; x.i = ((unsigned int)u) << 16; return x.f;
}

// ---------------- K0: Wt16[n][k] = bf16(W[k][n]) ----------------
__global__ __launch_bounds__(256) void convertWt(const float* __restrict__ W,
                                                 ushort* __restrict__ Wt) {
    int i = blockIdx.x * 256 + threadIdx.x;
    if (i >= DD * DD) return;
    int k = i >> 7, n = i & 127;
    Wt[n * DD + k] = f2bf(W[i]);
}

// ---------------- K1: Xp16 = bf16( X @ W ) via MFMA ----------------
__global__ __launch_bounds__(256) void gemm_mfma(const float* __restrict__ X,
                                                 const ushort* __restrict__ Wt,
                                                 ushort* __restrict__ Xp16) {
    __shared__ char WtL[DD * DD * 2];   // 32 KB, XOR-swizzled 16B chunks
    for (int c = threadIdx.x; c < 2048; c += 256) {
        int n = c >> 4, kc = c & 15;
        int dst = (n * 256 + kc * 16) ^ ((n & 7) << 4);
        *reinterpret_cast<int4*>(WtL + dst) = reinterpret_cast<const int4*>(Wt)[c];
    }
    __syncthreads();
    int wave = threadIdx.x >> 6;
    int lane = threadIdx.x & 63;
    int rowTile = blockIdx.x * 4 + wave;
    if (rowTile >= NN / 16) return;
    int r = lane & 15, half = lane >> 4;
    const float* xrow = X + (size_t)(rowTile * 16 + r) * DD;
    f32x4 acc[8];
    #pragma unroll
    for (int nt = 0; nt < 8; ++nt) acc[nt] = (f32x4)(0.f);
    #pragma unroll
    for (int kk = 0; kk < DD; kk += 32) {
        int kbase = kk + half * 8;
        float4 xa = *reinterpret_cast<const float4*>(xrow + kbase);
        float4 xb = *reinterpret_cast<const float4*>(xrow + kbase + 4);
        bf16x8 a;
        a[0] = (short)f2bf(xa.x); a[1] = (short)f2bf(xa.y);
        a[2] = (short)f2bf(xa.z); a[3] = (short)f2bf(xa.w);
        a[4] = (short)f2bf(xb.x); a[5] = (short)f2bf(xb.y);
        a[6] = (short)f2bf(xb.z); a[7] = (short)f2bf(xb.w);
        #pragma unroll
        for (int nt = 0; nt < 8; ++nt) {
            int n = nt * 16 + r;
            int off = (n * 256 + kbase * 2) ^ ((n & 7) << 4);
            bf16x8 b = *reinterpret_cast<const bf16x8*>(WtL + off);
            acc[nt] = __builtin_amdgcn_mfma_f32_16x16x32_bf16(a, b, acc[nt], 0, 0, 0);
        }
    }
    int row0 = rowTile * 16 + half * 4;   // C/D: col=lane&15, row=(lane>>4)*4+q
    #pragma unroll
    for (int nt = 0; nt < 8; ++nt)
        #pragma unroll
        for (int q = 0; q < 4; ++q)
            Xp16[(size_t)(row0 + q) * DD + nt * 16 + r] = f2bf(acc[nt][q]);
}

// ------- K2: per-bucket histogram, LDS-privatized (294 counters) -------
__global__ __launch_bounds__(256) void bucket_hist(const int* __restrict__ vertex,
                                                   const int* __restrict__ edges,
                                                   int* __restrict__ gEcnt,
                                                   int* __restrict__ gVcnt) {
    __shared__ int cE[NBE], cV[NBV];
    const int t = threadIdx.x;
    for (int i = t; i < NBE; i += 256) cE[i] = 0;
    for (int i = t; i < NBV; i += 256) cV[i] = 0;
    __syncthreads();
    int base = blockIdx.x * CH + t * 8;
    if (base + 7 < NNZP) {      // NNZP % 8 == 0: threads fully in or out
        int4 e0 = *reinterpret_cast<const int4*>(edges + base);
        int4 e1 = *reinterpret_cast<const int4*>(edges + base + 4);
        int4 v0 = *reinterpret_cast<const int4*>(vertex + base);
        int4 v1 = *reinterpret_cast<const int4*>(vertex + base + 4);
        atomicAdd(&cE[e0.x >> 9], 1); atomicAdd(&cE[e0.y >> 9], 1);
        atomicAdd(&cE[e0.z >> 9], 1); atomicAdd(&cE[e0.w >> 9], 1);
        atomicAdd(&cE[e1.x >> 9], 1); atomicAdd(&cE[e1.y >> 9], 1);
        atomicAdd(&cE[e1.z >> 9], 1); atomicAdd(&cE[e1.w >> 9], 1);
        atomicAdd(&cV[v0.x >> 9], 1); atomicAdd(&cV[v0.y >> 9], 1);
        atomicAdd(&cV[v0.z >> 9], 1); atomicAdd(&cV[v0.w >> 9], 1);
        atomicAdd(&cV[v1.x >> 9], 1); atomicAdd(&cV[v1.y >> 9], 1);
        atomicAdd(&cV[v1.z >> 9], 1); atomicAdd(&cV[v1.w >> 9], 1);
    }
    __syncthreads();
    for (int i = t; i < NBE; i += 256) if (cE[i]) atomicAdd(&gEcnt[i], cE[i]);
    for (int i = t; i < NBV; i += 256) if (cV[i]) atomicAdd(&gVcnt[i], cV[i]);
}

// ------- K3: scan 294 bucket counts -> bases + cursors; fixed tails -------
__global__ __launch_bounds__(512) void bucket_scan(const int* __restrict__ gCnt,  // [NBT]
                                                   int* __restrict__ eBase,       // [NBE+1]
                                                   int* __restrict__ vBase,       // [NBV+1]
                                                   int* __restrict__ gEcur,
                                                   int* __restrict__ gVcur,
                                                   int* __restrict__ eoff,
                                                   int* __restrict__ voff) {
    __shared__ int sh[512];
    int t = threadIdx.x;
    int v = (t < NBT) ? gCnt[t] : 0;
    sh[t] = v;
    __syncthreads();
    for (int d = 1; d < 512; d <<= 1) {
        int x = (t >= d) ? sh[t - d] : 0;
        __syncthreads();
        sh[t] += x;
        __syncthreads();
    }
    int excl = sh[t] - v;     // exclusive scan; edge buckets sum to NNZP
    if (t < NBE)      { eBase[t] = excl;        gEcur[t] = excl; }
    else if (t < NBT) { vBase[t - NBE] = excl - NNZP; gVcur[t - NBE] = excl - NNZP; }
    if (t == 0) { eBase[NBE] = NNZP; vBase[NBV] = NNZP; eoff[NE] = NNZP; voff[NN] = NNZP; }
}

// ------- K4: bucket both directions; block-contiguous runs -> coalesced writes ----
__global__ __launch_bounds__(256) void bucket_scatter(const int* __restrict__ vertex,
                                                      const int* __restrict__ edges,
                                                      int* __restrict__ gEcur,
                                                      int* __restrict__ gVcur,
                                                      int2* __restrict__ ebuck,
                                                      int2* __restrict__ vbuck) {
    __shared__ int cE[NBE], bE[NBE], cV[NBV], bV[NBV];
    const int t = threadIdx.x;
    for (int i = t; i < NBE; i += 256) cE[i] = 0;
    for (int i = t; i < NBV; i += 256) cV[i] = 0;
    __syncthreads();
    const int base = blockIdx.x * CH;
    int e[8], v[8];
    #pragma unroll
    for (int k = 0; k < 8; ++k) {
        int idx = base + k * 256 + t;
        if (idx < NNZP) {
            e[k] = edges[idx]; v[k] = vertex[idx];
            atomicAdd(&cE[e[k] >> 9], 1);
            atomicAdd(&cV[v[k] >> 9], 1);
        } else e[k] = -1;
    }
    __syncthreads();
    for (int i = t; i < NBE; i += 256) {
        int c = cE[i];
        bE[i] = c ? atomicAdd(&gEcur[i], c) : 0;
        cE[i] = 0;
    }
    for (int i = t; i < NBV; i += 256) {
        int c = cV[i];
        bV[i] = c ? atomicAdd(&gVcur[i], c) : 0;
        cV[i] = 0;
    }
    __syncthreads();
    #pragma unroll
    for (int k = 0; k < 8; ++k) {
        if (e[k] >= 0) {
            int be = e[k] >> 9, bv = v[k] >> 9;
            int pe = bE[be] + atomicAdd(&cE[be], 1);
            ebuck[pe] = make_int2(e[k], v[k]);
            int pv = bV[bv] + atomicAdd(&cV[bv], 1);
            vbuck[pv] = make_int2(v[k], e[k]);
        }
    }
}

// ------- K5: per bucket: LDS per-id hist + scan -> eoff/voff, then place ----
__global__ __launch_bounds__(256) void place_buckets2(const int2* __restrict__ ebuck,
                                                      const int2* __restrict__ vbuck,
                                                      const int* __restrict__ eBase,
                                                      const int* __restrict__ vBase,
                                                      int* __restrict__ eoff,
                                                      int* __restrict__ voff,
                                                      int* __restrict__ vlist,
                                                      int* __restrict__ elist) {
    __shared__ int cnt[EBK];
    __shared__ int wsum[4];
    const int t = threadIdx.x;
    int b = blockIdx.x;
    const int2* buck; int id0, nid, start, end; int* off; int* lst;
    if (b < NBE) {
        buck = ebuck; id0 = b * EBK; nid = min(EBK, NE - id0);
        start = eBase[b]; end = eBase[b + 1]; off = eoff; lst = vlist;
    } else {
        b -= NBE;
        buck = vbuck; id0 = b * VBK; nid = min(VBK, NN - id0);
        start = vBase[b]; end = vBase[b + 1]; off = voff; lst = elist;
    }
    for (int i = t; i < nid; i += 256) cnt[i] = 0;
    __syncthreads();
    // pass 1: per-id histogram of this bucket's run
    for (int i = start + t; i < end; i += 256)
        atomicAdd(&cnt[buck[i].x - id0], 1);
    __syncthreads();
    // exclusive scan of cnt[0..nid) (each thread owns elements 2t, 2t+1)
    int c0 = (2 * t     < nid) ? cnt[2 * t]     : 0;
    int c1 = (2 * t + 1 < nid) ? cnt[2 * t + 1] : 0;
    int s = c0 + c1;
    int inc = s;
    #pragma unroll
    for (int d = 1; d < 64; d <<= 1) {
        int x = __shfl_up(inc, d, 64);
        if ((t & 63) >= d) inc += x;
    }
    if ((t & 63) == 63) wsum[t >> 6] = inc;
    __syncthreads();
    int wid = t >> 6, wbase = 0;
    #pragma unroll
    for (int w = 0; w < 3; ++w) if (w < wid) wbase += wsum[w];
    int excl = start + wbase + (inc - s);   // global CSR offset for id 2t
    if (2 * t     < nid) off[id0 + 2 * t]     = excl;
    if (2 * t + 1 < nid) off[id0 + 2 * t + 1] = excl + c0;
    __syncthreads();
    if (2 * t     < nid) cnt[2 * t]     = excl;        // cursors
    if (2 * t + 1 < nid) cnt[2 * t + 1] = excl + c0;
    __syncthreads();
    // pass 2: place payloads at final CSR slots
    for (int i = start + t; i < end; i += 256) {
        int2 p = buck[i];
        lst[atomicAdd(&cnt[p.x - id0], 1)] = p.y;
    }
}

// ---------------- K6: Xe[e] = mean of Xp16 rows; also Xe16 ----------------
__global__ __launch_bounds__(256) void edge_gather(const ushort* __restrict__ Xp16,
                                                   const int* __restrict__ eoff,
                                                   const int* __restrict__ vlist,
                                                   float* __restrict__ Xe,
                                                   ushort* __restrict__ Xe16) {
    int e = blockIdx.x * 8 + (threadIdx.x >> 5);
    if (e >= NE) return;
    int lane = threadIdx.x & 31;
    int start = eoff[e], end = eoff[e + 1];
    float ax = 0.f, ay = 0.f, az = 0.f, aw = 0.f;
    int j = start;
    for (; j + 3 < end; j += 4) {
        int v0 = vlist[j], v1 = vlist[j + 1], v2 = vlist[j + 2], v3 = vlist[j + 3];
        ushort4 x0 = *reinterpret_cast<const ushort4*>(Xp16 + (size_t)v0 * DD + lane * 4);
        ushort4 x1 = *reinterpret_cast<const ushort4*>(Xp16 + (size_t)v1 * DD + lane * 4);
        ushort4 x2 = *reinterpret_cast<const ushort4*>(Xp16 + (size_t)v2 * DD + lane * 4);
        ushort4 x3 = *reinterpret_cast<const ushort4*>(Xp16 + (size_t)v3 * DD + lane * 4);
        ax += bf2f(x0.x) + bf2f(x1.x) + bf2f(x2.x) + bf2f(x3.x);
        ay += bf2f(x0.y) + bf2f(x1.y) + bf2f(x2.y) + bf2f(x3.y);
        az += bf2f(x0.z) + bf2f(x1.z) + bf2f(x2.z) + bf2f(x3.z);
        aw += bf2f(x0.w) + bf2f(x1.w) + bf2f(x2.w) + bf2f(x3.w);
    }
    for (; j < end; ++j) {
        int v0 = vlist[j];
        ushort4 x0 = *reinterpret_cast<const ushort4*>(Xp16 + (size_t)v0 * DD + lane * 4);
        ax += bf2f(x0.x); ay += bf2f(x0.y); az += bf2f(x0.z); aw += bf2f(x0.w);
    }
    float inv = 1.0f / fmaxf((float)(end - start), 1.0f);
    float4 o = make_float4(ax * inv, ay * inv, az * inv, aw * inv);
    *reinterpret_cast<float4*>(Xe + (size_t)e * DD + lane * 4) = o;
    ushort4 h;
    h.x = f2bf(o.x); h.y = f2bf(o.y); h.z = f2bf(o.z); h.w = f2bf(o.w);
    *reinterpret_cast<ushort4*>(Xe16 + (size_t)e * DD + lane * 4) = h;
}

// -------- K7: Xv = sum Xe16 rows; out = normalize((1+eps)*Xp + Xv) --------
__global__ __launch_bounds__(256) void vertex_gather_out(const ushort* __restrict__ Xp16,
                                                         const ushort* __restrict__ Xe16,
                                                         const int* __restrict__ voff,
                                                         const int* __restrict__ elist,
                                                         const float* __restrict__ eps,
                                                         float* __restrict__ Out) {
    int v = blockIdx.x * 8 + (threadIdx.x >> 5);
    if (v >= NN) return;
    int lane = threadIdx.x & 31;
    int start = voff[v], end = voff[v + 1];
    float ax = 0.f, ay = 0.f, az = 0.f, aw = 0.f;
    int j = start;
    for (; j + 3 < end; j += 4) {
        int e0 = elist[j], e1 = elist[j + 1], e2 = elist[j + 2], e3 = elist[j + 3];
        ushort4 x0 = *reinterpret_cast<const ushort4*>(Xe16 + (size_t)e0 * DD + lane * 4);
        ushort4 x1 = *reinterpret_cast<const ushort4*>(Xe16 + (size_t)e1 * DD + lane * 4);
        ushort4 x2 = *reinterpret_cast<const ushort4*>(Xe16 + (size_t)e2 * DD + lane * 4);
        ushort4 x3 = *reinterpret_cast<const ushort4*>(Xe16 + (size_t)e3 * DD + lane * 4);
        ax += bf2f(x0.x) + bf2f(x1.x) + bf2f(x2.x) + bf2f(x3.x);
        ay += bf2f(x0.y) + bf2f(x1.y) + bf2f(x2.y) + bf2f(x3.y);
        az += bf2f(x0.z) + bf2f(x1.z) + bf2f(x2.z) + bf2f(x3.z);
        aw += bf2f(x0.w) + bf2f(x1.w) + bf2f(x2.w) + bf2f(x3.w);
    }
    for (; j < end; ++j) {
        int e0 = elist[j];
        ushort4 x0 = *reinterpret_cast<const ushort4*>(Xe16 + (size_t)e0 * DD + lane * 4);
        ax += bf2f(x0.x); ay += bf2f(x0.y); az += bf2f(x0.z); aw += bf2f(x0.w);
    }
    float g = 1.0f + eps[0];
    ushort4 xp = *reinterpret_cast<const ushort4*>(Xp16 + (size_t)v * DD + lane * 4);
    float4 o;
    o.x = fmaf(g, bf2f(xp.x), ax);
    o.y = fmaf(g, bf2f(xp.y), ay);
    o.z = fmaf(g, bf2f(xp.z), az);
    o.w = fmaf(g, bf2f(xp.w), aw);
    float ss = o.x * o.x + o.y * o.y + o.z * o.z + o.w * o.w;
    #pragma unroll
    for (int off = 1; off < 32; off <<= 1) ss += __shfl_xor(ss, off, 64);
    float inv = 1.0f / fmaxf(sqrtf(ss), 1e-12f);
    o.x *= inv; o.y *= inv; o.z *= inv; o.w *= inv;
    *reinterpret_cast<float4*>(Out + (size_t)v * DD + lane * 4) = o;
}

extern "C" void kernel_launch(void* const* d_in, const int* in_sizes, int n_in,
                              void* d_out, int out_size, void* d_ws, size_t ws_size,
                              hipStream_t stream) {
    const float* X      = (const float*)d_in[0];
    const float* W      = (const float*)d_in[1];
    const float* eps    = (const float*)d_in[2];
    const int*   vertex = (const int*)d_in[3];
    const int*   edges  = (const int*)d_in[4];

    float* out = (float*)d_out;                 // [N,D] — scratch for buckets until K7
    float* Xe  = out + (size_t)NN * DD;         // [E,D]

    // bucket arrays live in the 'out' region (dead until vertex_gather_out rewrites it)
    int2* ebuck = (int2*)out;                   // NNZ int2 = 12.8 MB
    int2* vbuck = ebuck + NNZP;                 // NNZ int2 = 12.8 MB (total 25.6 <= 51.2)

    // workspace layout (~52 MB)
    ushort* Xp16 = (ushort*)d_ws;                        // N*D bf16
    ushort* Xe16 = Xp16 + (size_t)NN * DD;               // E*D bf16
    ushort* Wt16 = Xe16 + (size_t)NE * DD;               // D*D bf16
    int*    eoff = (int*)(Wt16 + DD * DD);               // E+1
    int*    voff = eoff + NE + 1;                        // N+1
    int*    vlist = voff + NN + 1;                       // NNZ
    int*    elist = vlist + NNZP;                        // NNZ
    int*    gEcnt = elist + NNZP;                        // NBE   (contiguous with gVcnt)
    int*    gVcnt = gEcnt + NBE;                         // NBV
    int*    gEcur = gVcnt + NBV;                         // NBE
    int*    gVcur = gEcur + NBE;                         // NBV
    int*    eBase = gVcur + NBV;                         // NBE+1
    int*    vBase = eBase + NBE + 1;                     // NBV+1

    hipMemsetAsync(gEcnt, 0, (size_t)NBT * sizeof(int), stream);

    convertWt<<<(DD * DD + 255) / 256, 256, 0, stream>>>(W, Wt16);
    gemm_mfma<<<(NN / 16 + 3) / 4, 256, 0, stream>>>(X, Wt16, Xp16);
    bucket_hist<<<NCHB, 256, 0, stream>>>(vertex, edges, gEcnt, gVcnt);
    bucket_scan<<<1, 512, 0, stream>>>(gEcnt, eBase, vBase, gEcur, gVcur, eoff, voff);
    bucket_scatter<<<NCHB, 256, 0, stream>>>(vertex, edges, gEcur, gVcur, ebuck, vbuck);
    place_buckets2<<<NBT, 256, 0, stream>>>(ebuck, vbuck, eBase, vBase, eoff, voff, vlist, elist);
    edge_gather<<<NE / 8, 256, 0, stream>>>(Xp16, eoff, vlist, Xe, Xe16);
    vertex_gather_out<<<NN / 8, 256, 0, stream>>>(Xp16, Xe16, voff, elist, eps, out);
}

// Round 8
// 251.851 us; speedup vs baseline: 22.1135x; 1.0591x over previous
//
#include <hip/hip_runtime.h>
#include <hip/hip_bf16.h>

#define NN   100000
#define NE   50000
#define NNZP 1600000
#define DD   128

#define EBK  512
#define NBE  ((NE + EBK - 1) / EBK)             // 98
#define VBK  512
#define NBV  ((NN + VBK - 1) / VBK)             // 196
#define NBT  (NBE + NBV)                        // 294
#define CH   2048                               // pairs per hist block
#define NCHB ((NNZP + CH - 1) / CH)             // 782
#define CH2  6250                               // pairs per scatter block (256 * 6250 == NNZP)

typedef __attribute__((ext_vector_type(8))) short bf16x8;
typedef __attribute__((ext_vector_type(4))) float f32x4;

__device__ __forceinline__ ushort f2bf(float f) {
    __hip_bfloat16 h = __float2bfloat16(f);
    return *reinterpret_cast<ushort*>(&h);
}
__device__ __forceinline__ void acc4(uint2 u, float& ax, float& ay, float& az, float& aw) {
    ax += __uint_as_float(u.x << 16);
    ay += __uint_as_float(u.x & 0xffff0000u);
    az += __uint_as_float(u.y << 16);
    aw += __uint_as_float(u.y & 0xffff0000u);
}

// ------- K1: fused per-bucket histogram (LDS-privatized) + Wt convert -------
__global__ __launch_bounds__(256) void hist_convert(const int* __restrict__ vertex,
                                                    const int* __restrict__ edges,
                                                    int* __restrict__ gEcnt,
                                                    int* __restrict__ gVcnt,
                                                    const float* __restrict__ W,
                                                    ushort* __restrict__ Wt) {
    __shared__ int cE[NBE], cV[NBV];
    const int t = threadIdx.x;
    if (blockIdx.x >= NCHB) {       // tail blocks: Wt16[n][k] = bf16(W[k][n])
        int i = (blockIdx.x - NCHB) * 256 + t;
        if (i < DD * DD) { int k = i >> 7, n = i & 127; Wt[n * DD + k] = f2bf(W[i]); }
        return;
    }
    for (int i = t; i < NBE; i += 256) cE[i] = 0;
    for (int i = t; i < NBV; i += 256) cV[i] = 0;
    __syncthreads();
    int base = blockIdx.x * CH + t * 8;
    if (base + 7 < NNZP) {
        int4 e0 = *reinterpret_cast<const int4*>(edges + base);
        int4 e1 = *reinterpret_cast<const int4*>(edges + base + 4);
        int4 v0 = *reinterpret_cast<const int4*>(vertex + base);
        int4 v1 = *reinterpret_cast<const int4*>(vertex + base + 4);
        atomicAdd(&cE[e0.x >> 9], 1); atomicAdd(&cE[e0.y >> 9], 1);
        atomicAdd(&cE[e0.z >> 9], 1); atomicAdd(&cE[e0.w >> 9], 1);
        atomicAdd(&cE[e1.x >> 9], 1); atomicAdd(&cE[e1.y >> 9], 1);
        atomicAdd(&cE[e1.z >> 9], 1); atomicAdd(&cE[e1.w >> 9], 1);
        atomicAdd(&cV[v0.x >> 9], 1); atomicAdd(&cV[v0.y >> 9], 1);
        atomicAdd(&cV[v0.z >> 9], 1); atomicAdd(&cV[v0.w >> 9], 1);
        atomicAdd(&cV[v1.x >> 9], 1); atomicAdd(&cV[v1.y >> 9], 1);
        atomicAdd(&cV[v1.z >> 9], 1); atomicAdd(&cV[v1.w >> 9], 1);
    }
    __syncthreads();
    for (int i = t; i < NBE; i += 256) if (cE[i]) atomicAdd(&gEcnt[i], cE[i]);
    for (int i = t; i < NBV; i += 256) if (cV[i]) atomicAdd(&gVcnt[i], cV[i]);
}

// ---------------- K2: Xp16 = bf16( X @ W ) via MFMA (2 rowTiles/wave) ----------------
__global__ __launch_bounds__(256) void gemm_mfma(const float* __restrict__ X,
                                                 const ushort* __restrict__ Wt,
                                                 ushort* __restrict__ Xp16) {
    __shared__ char WtL[DD * DD * 2];   // 32 KB, XOR-swizzled 16B chunks
    for (int c = threadIdx.x; c < 2048; c += 256) {
        int n = c >> 4, kc = c & 15;
        int dst = (n * 256 + kc * 16) ^ ((n & 7) << 4);
        *reinterpret_cast<int4*>(WtL + dst) = reinterpret_cast<const int4*>(Wt)[c];
    }
    __syncthreads();
    int wave = threadIdx.x >> 6;
    int lane = threadIdx.x & 63;
    int r = lane & 15, half = lane >> 4;
    #pragma unroll
    for (int rt = 0; rt < 2; ++rt) {
        int rowTile = blockIdx.x * 8 + wave * 2 + rt;
        if (rowTile >= NN / 16) break;
        const float* xrow = X + (size_t)(rowTile * 16 + r) * DD;
        f32x4 acc[8];
        #pragma unroll
        for (int nt = 0; nt < 8; ++nt) acc[nt] = (f32x4)(0.f);
        #pragma unroll
        for (int kk = 0; kk < DD; kk += 32) {
            int kbase = kk + half * 8;
            float4 xa = *reinterpret_cast<const float4*>(xrow + kbase);
            float4 xb = *reinterpret_cast<const float4*>(xrow + kbase + 4);
            bf16x8 a;
            a[0] = (short)f2bf(xa.x); a[1] = (short)f2bf(xa.y);
            a[2] = (short)f2bf(xa.z); a[3] = (short)f2bf(xa.w);
            a[4] = (short)f2bf(xb.x); a[5] = (short)f2bf(xb.y);
            a[6] = (short)f2bf(xb.z); a[7] = (short)f2bf(xb.w);
            #pragma unroll
            for (int nt = 0; nt < 8; ++nt) {
                int n = nt * 16 + r;
                int off = (n * 256 + kbase * 2) ^ ((n & 7) << 4);
                bf16x8 b = *reinterpret_cast<const bf16x8*>(WtL + off);
                acc[nt] = __builtin_amdgcn_mfma_f32_16x16x32_bf16(a, b, acc[nt], 0, 0, 0);
            }
        }
        int row0 = rowTile * 16 + half * 4;   // C/D: col=lane&15, row=(lane>>4)*4+q
        #pragma unroll
        for (int nt = 0; nt < 8; ++nt)
            #pragma unroll
            for (int q = 0; q < 4; ++q)
                Xp16[(size_t)(row0 + q) * DD + nt * 16 + r] = f2bf(acc[nt][q]);
    }
}

// ------- K3: scan 294 bucket counts -> bases + cursors; fixed tails -------
__global__ __launch_bounds__(512) void bucket_scan(const int* __restrict__ gCnt,  // [NBT]
                                                   int* __restrict__ eBase,       // [NBE+1]
                                                   int* __restrict__ vBase,       // [NBV+1]
                                                   int* __restrict__ gEcur,
                                                   int* __restrict__ gVcur,
                                                   int* __restrict__ eoff,
                                                   int* __restrict__ voff) {
    __shared__ int sh[512];
    int t = threadIdx.x;
    int v = (t < NBT) ? gCnt[t] : 0;
    sh[t] = v;
    __syncthreads();
    for (int d = 1; d < 512; d <<= 1) {
        int x = (t >= d) ? sh[t - d] : 0;
        __syncthreads();
        sh[t] += x;
        __syncthreads();
    }
    int excl = sh[t] - v;     // exclusive scan; edge buckets sum to NNZP
    if (t < NBE)      { eBase[t] = excl;        gEcur[t] = excl; }
    else if (t < NBT) { vBase[t - NBE] = excl - NNZP; gVcur[t - NBE] = excl - NNZP; }
    if (t == 0) { eBase[NBE] = NNZP; vBase[NBV] = NNZP; eoff[NE] = NNZP; voff[NN] = NNZP; }
}

// ------- K4: 2-pass bucket scatter: count -> reserve -> place (long runs) -------
__global__ __launch_bounds__(256) void bucket_scatter2(const int* __restrict__ vertex,
                                                       const int* __restrict__ edges,
                                                       int* __restrict__ gEcur,
                                                       int* __restrict__ gVcur,
                                                       int2* __restrict__ ebuck,
                                                       int2* __restrict__ vbuck) {
    __shared__ int cE[NBE], bE[NBE], cV[NBV], bV[NBV];
    const int t = threadIdx.x;
    const int base = blockIdx.x * CH2;          // CH2 even; 256*CH2 == NNZP
    for (int i = t; i < NBE; i += 256) cE[i] = 0;
    for (int i = t; i < NBV; i += 256) cV[i] = 0;
    __syncthreads();
    // pass 1: count (int2 loads)
    for (int i = t; i < CH2 / 2; i += 256) {
        int2 e2 = *reinterpret_cast<const int2*>(edges + base + i * 2);
        int2 v2 = *reinterpret_cast<const int2*>(vertex + base + i * 2);
        atomicAdd(&cE[e2.x >> 9], 1); atomicAdd(&cE[e2.y >> 9], 1);
        atomicAdd(&cV[v2.x >> 9], 1); atomicAdd(&cV[v2.y >> 9], 1);
    }
    __syncthreads();
    // reserve contiguous runs
    for (int i = t; i < NBE; i += 256) {
        int c = cE[i];
        bE[i] = c ? atomicAdd(&gEcur[i], c) : 0;
        cE[i] = 0;
    }
    for (int i = t; i < NBV; i += 256) {
        int c = cV[i];
        bV[i] = c ? atomicAdd(&gVcur[i], c) : 0;
        cV[i] = 0;
    }
    __syncthreads();
    // pass 2: place (re-read, L2-hot)
    for (int i = t; i < CH2 / 2; i += 256) {
        int2 e2 = *reinterpret_cast<const int2*>(edges + base + i * 2);
        int2 v2 = *reinterpret_cast<const int2*>(vertex + base + i * 2);
        int pe0 = bE[e2.x >> 9] + atomicAdd(&cE[e2.x >> 9], 1);
        ebuck[pe0] = make_int2(e2.x, v2.x);
        int pe1 = bE[e2.y >> 9] + atomicAdd(&cE[e2.y >> 9], 1);
        ebuck[pe1] = make_int2(e2.y, v2.y);
        int pv0 = bV[v2.x >> 9] + atomicAdd(&cV[v2.x >> 9], 1);
        vbuck[pv0] = make_int2(v2.x, e2.x);
        int pv1 = bV[v2.y >> 9] + atomicAdd(&cV[v2.y >> 9], 1);
        vbuck[pv1] = make_int2(v2.y, e2.y);
    }
}

// ------- K5: per bucket: LDS per-id hist + scan -> eoff/voff, then place ----
__global__ __launch_bounds__(256) void place_buckets2(const int2* __restrict__ ebuck,
                                                      const int2* __restrict__ vbuck,
                                                      const int* __restrict__ eBase,
                                                      const int* __restrict__ vBase,
                                                      int* __restrict__ eoff,
                                                      int* __restrict__ voff,
                                                      int* __restrict__ vlist,
                                                      int* __restrict__ elist) {
    __shared__ int cnt[EBK];
    __shared__ int wsum[4];
    const int t = threadIdx.x;
    int b = blockIdx.x;
    const int2* buck; int id0, nid, start, end; int* off; int* lst;
    if (b < NBE) {
        buck = ebuck; id0 = b * EBK; nid = min(EBK, NE - id0);
        start = eBase[b]; end = eBase[b + 1]; off = eoff; lst = vlist;
    } else {
        b -= NBE;
        buck = vbuck; id0 = b * VBK; nid = min(VBK, NN - id0);
        start = vBase[b]; end = vBase[b + 1]; off = voff; lst = elist;
    }
    for (int i = t; i < nid; i += 256) cnt[i] = 0;
    __syncthreads();
    for (int i = start + t; i < end; i += 256)
        atomicAdd(&cnt[buck[i].x - id0], 1);
    __syncthreads();
    int c0 = (2 * t     < nid) ? cnt[2 * t]     : 0;
    int c1 = (2 * t + 1 < nid) ? cnt[2 * t + 1] : 0;
    int s = c0 + c1;
    int inc = s;
    #pragma unroll
    for (int d = 1; d < 64; d <<= 1) {
        int x = __shfl_up(inc, d, 64);
        if ((t & 63) >= d) inc += x;
    }
    if ((t & 63) == 63) wsum[t >> 6] = inc;
    __syncthreads();
    int wid = t >> 6, wbase = 0;
    #pragma unroll
    for (int w = 0; w < 3; ++w) if (w < wid) wbase += wsum[w];
    int excl = start + wbase + (inc - s);
    if (2 * t     < nid) off[id0 + 2 * t]     = excl;
    if (2 * t + 1 < nid) off[id0 + 2 * t + 1] = excl + c0;
    __syncthreads();
    if (2 * t     < nid) cnt[2 * t]     = excl;
    if (2 * t + 1 < nid) cnt[2 * t + 1] = excl + c0;
    __syncthreads();
    for (int i = start + t; i < end; i += 256) {
        int2 p = buck[i];
        lst[atomicAdd(&cnt[p.x - id0], 1)] = p.y;
    }
}

// ---------------- K6: Xe[e] = mean of Xp16 rows; also Xe16 ----------------
__global__ __launch_bounds__(256) void edge_gather(const ushort* __restrict__ Xp16,
                                                   const int* __restrict__ eoff,
                                                   const int* __restrict__ vlist,
                                                   float* __restrict__ Xe,
                                                   ushort* __restrict__ Xe16) {
    int e = blockIdx.x * 8 + (threadIdx.x >> 5);
    if (e >= NE) return;
    int lane = threadIdx.x & 31;
    int start = eoff[e], end = eoff[e + 1];
    float ax = 0.f, ay = 0.f, az = 0.f, aw = 0.f;
    int j = start;
    for (; j + 7 < end; j += 8) {
        int v0 = vlist[j],     v1 = vlist[j + 1], v2 = vlist[j + 2], v3 = vlist[j + 3];
        int v4 = vlist[j + 4], v5 = vlist[j + 5], v6 = vlist[j + 6], v7 = vlist[j + 7];
        uint2 u0 = *reinterpret_cast<const uint2*>(Xp16 + (size_t)v0 * DD + lane * 4);
        uint2 u1 = *reinterpret_cast<const uint2*>(Xp16 + (size_t)v1 * DD + lane * 4);
        uint2 u2 = *reinterpret_cast<const uint2*>(Xp16 + (size_t)v2 * DD + lane * 4);
        uint2 u3 = *reinterpret_cast<const uint2*>(Xp16 + (size_t)v3 * DD + lane * 4);
        uint2 u4 = *reinterpret_cast<const uint2*>(Xp16 + (size_t)v4 * DD + lane * 4);
        uint2 u5 = *reinterpret_cast<const uint2*>(Xp16 + (size_t)v5 * DD + lane * 4);
        uint2 u6 = *reinterpret_cast<const uint2*>(Xp16 + (size_t)v6 * DD + lane * 4);
        uint2 u7 = *reinterpret_cast<const uint2*>(Xp16 + (size_t)v7 * DD + lane * 4);
        acc4(u0, ax, ay, az, aw); acc4(u1, ax, ay, az, aw);
        acc4(u2, ax, ay, az, aw); acc4(u3, ax, ay, az, aw);
        acc4(u4, ax, ay, az, aw); acc4(u5, ax, ay, az, aw);
        acc4(u6, ax, ay, az, aw); acc4(u7, ax, ay, az, aw);
    }
    for (; j < end; ++j) {
        uint2 u = *reinterpret_cast<const uint2*>(Xp16 + (size_t)vlist[j] * DD + lane * 4);
        acc4(u, ax, ay, az, aw);
    }
    float inv = 1.0f / fmaxf((float)(end - start), 1.0f);
    float4 o = make_float4(ax * inv, ay * inv, az * inv, aw * inv);
    *reinterpret_cast<float4*>(Xe + (size_t)e * DD + lane * 4) = o;
    ushort4 h;
    h.x = f2bf(o.x); h.y = f2bf(o.y); h.z = f2bf(o.z); h.w = f2bf(o.w);
    *reinterpret_cast<ushort4*>(Xe16 + (size_t)e * DD + lane * 4) = h;
}

// -------- K7: Xv = sum Xe16 rows; out = normalize((1+eps)*Xp + Xv) --------
__global__ __launch_bounds__(256) void vertex_gather_out(const ushort* __restrict__ Xp16,
                                                         const ushort* __restrict__ Xe16,
                                                         const int* __restrict__ voff,
                                                         const int* __restrict__ elist,
                                                         const float* __restrict__ eps,
                                                         float* __restrict__ Out) {
    int v = blockIdx.x * 8 + (threadIdx.x >> 5);
    if (v >= NN) return;
    int lane = threadIdx.x & 31;
    int start = voff[v], end = voff[v + 1];
    float ax = 0.f, ay = 0.f, az = 0.f, aw = 0.f;
    int j = start;
    for (; j + 7 < end; j += 8) {
        int e0 = elist[j],     e1 = elist[j + 1], e2 = elist[j + 2], e3 = elist[j + 3];
        int e4 = elist[j + 4], e5 = elist[j + 5], e6 = elist[j + 6], e7 = elist[j + 7];
        uint2 u0 = *reinterpret_cast<const uint2*>(Xe16 + (size_t)e0 * DD + lane * 4);
        uint2 u1 = *reinterpret_cast<const uint2*>(Xe16 + (size_t)e1 * DD + lane * 4);
        uint2 u2 = *reinterpret_cast<const uint2*>(Xe16 + (size_t)e2 * DD + lane * 4);
        uint2 u3 = *reinterpret_cast<const uint2*>(Xe16 + (size_t)e3 * DD + lane * 4);
        uint2 u4 = *reinterpret_cast<const uint2*>(Xe16 + (size_t)e4 * DD + lane * 4);
        uint2 u5 = *reinterpret_cast<const uint2*>(Xe16 + (size_t)e5 * DD + lane * 4);
        uint2 u6 = *reinterpret_cast<const uint2*>(Xe16 + (size_t)e6 * DD + lane * 4);
        uint2 u7 = *reinterpret_cast<const uint2*>(Xe16 + (size_t)e7 * DD + lane * 4);
        acc4(u0, ax, ay, az, aw); acc4(u1, ax, ay, az, aw);
        acc4(u2, ax, ay, az, aw); acc4(u3, ax, ay, az, aw);
        acc4(u4, ax, ay, az, aw); acc4(u5, ax, ay, az, aw);
        acc4(u6, ax, ay, az, aw); acc4(u7, ax, ay, az, aw);
    }
    for (; j < end; ++j) {
        uint2 u = *reinterpret_cast<const uint2*>(Xe16 + (size_t)elist[j] * DD + lane * 4);
        acc4(u, ax, ay, az, aw);
    }
    float g = 1.0f + eps[0];
    uint2 xp = *reinterpret_cast<const uint2*>(Xp16 + (size_t)v * DD + lane * 4);
    float4 o;
    o.x = fmaf(g, __uint_as_float(xp.x << 16),        ax);
    o.y = fmaf(g, __uint_as_float(xp.x & 0xffff0000u), ay);
    o.z = fmaf(g, __uint_as_float(xp.y << 16),        az);
    o.w = fmaf(g, __uint_as_float(xp.y & 0xffff0000u), aw);
    float ss = o.x * o.x + o.y * o.y + o.z * o.z + o.w * o.w;
    #pragma unroll
    for (int off = 1; off < 32; off <<= 1) ss += __shfl_xor(ss, off, 64);
    float inv = 1.0f / fmaxf(sqrtf(ss), 1e-12f);
    o.x *= inv; o.y *= inv; o.z *= inv; o.w *= inv;
    *reinterpret_cast<float4*>(Out + (size_t)v * DD + lane * 4) = o;
}

extern "C" void kernel_launch(void* const* d_in, const int* in_sizes, int n_in,
                              void* d_out, int out_size, void* d_ws, size_t ws_size,
                              hipStream_t stream) {
    const float* X      = (const float*)d_in[0];
    const float* W      = (const float*)d_in[1];
    const float* eps    = (const float*)d_in[2];
    const int*   vertex = (const int*)d_in[3];
    const int*   edges  = (const int*)d_in[4];

    float* out = (float*)d_out;                 // [N,D] — scratch for buckets until K7
    float* Xe  = out + (size_t)NN * DD;         // [E,D]

    // bucket arrays live in the 'out' region (dead until vertex_gather_out rewrites it)
    int2* ebuck = (int2*)out;                   // NNZ int2 = 12.8 MB
    int2* vbuck = ebuck + NNZP;                 // NNZ int2 = 12.8 MB (total 25.6 <= 51.2)

    // workspace layout (~52 MB)
    ushort* Xp16 = (ushort*)d_ws;                        // N*D bf16
    ushort* Xe16 = Xp16 + (size_t)NN * DD;               // E*D bf16
    ushort* Wt16 = Xe16 + (size_t)NE * DD;               // D*D bf16
    int*    eoff = (int*)(Wt16 + DD * DD);               // E+1
    int*    voff = eoff + NE + 1;                        // N+1
    int*    vlist = voff + NN + 1;                       // NNZ
    int*    elist = vlist + NNZP;                        // NNZ
    int*    gEcnt = elist + NNZP;                        // NBE   (contiguous with gVcnt)
    int*    gVcnt = gEcnt + NBE;                         // NBV
    int*    gEcur = gVcnt + NBV;                         // NBE
    int*    gVcur = gEcur + NBE;                         // NBV
    int*    eBase = gVcur + NBV;                         // NBE+1
    int*    vBase = eBase + NBE + 1;                     // NBV+1

    hipMemsetAsync(gEcnt, 0, (size_t)NBT * sizeof(int), stream);

    hist_convert<<<NCHB + 64, 256, 0, stream>>>(vertex, edges, gEcnt, gVcnt, W, Wt16);
    gemm_mfma<<<(NN / 16 + 7) / 8, 256, 0, stream>>>(X, Wt16, Xp16);
    bucket_scan<<<1, 512, 0, stream>>>(gEcnt, eBase, vBase, gEcur, gVcur, eoff, voff);
    bucket_scatter2<<<256, 256, 0, stream>>>(vertex, edges, gEcur, gVcur, ebuck, vbuck);
    place_buckets2<<<NBT, 256, 0, stream>>>(ebuck, vbuck, eBase, vBase, eoff, voff, vlist, elist);
    edge_gather<<<NE / 8, 256, 0, stream>>>(Xp16, eoff, vlist, Xe, Xe16);
    vertex_gather_out<<<NN / 8, 256, 0, stream>>>(Xp16, Xe16, voff, elist, eps, out);
}